// Round 3
// baseline (1012.009 us; speedup 1.0000x reference)
//
#include <hip/hip_runtime.h>
#include <hip/hip_bf16.h>
#include <math.h>

#define BB 2048   // batch per view
#define NN 4096   // 2*BB
#define DD 128    // feature dim
#define CC 512    // classes

typedef __attribute__((ext_vector_type(8))) short bf16x8;   // 8 bf16 = 4 VGPRs
typedef __attribute__((ext_vector_type(4))) float f32x4;

// ---------------- K1: l2-normalize the 6 inputs into 3 concatenated feats (fp32 + bf16) ----
__global__ void k_norm(const float* __restrict__ si, const float* __restrict__ sj,
                       const float* __restrict__ ci, const float* __restrict__ cj,
                       const float* __restrict__ pi, const float* __restrict__ pj,
                       float* __restrict__ feats, __hip_bfloat16* __restrict__ fbf) {
  const int row = blockIdx.x;   // 0..4095
  const int m   = blockIdx.y;   // 0..2
  const float* src;
  if (m == 0)      src = (row < BB) ? si : sj;
  else if (m == 1) src = (row < BB) ? ci : cj;
  else             src = (row < BB) ? pi : pj;
  const int r = (row < BB) ? row : row - BB;
  const float2* s2 = (const float2*)(src + (size_t)r * DD);
  const int t = threadIdx.x;    // 0..63
  float2 v = s2[t];
  float ss = v.x * v.x + v.y * v.y;
  #pragma unroll
  for (int k = 32; k >= 1; k >>= 1) ss += __shfl_xor(ss, k);
  const float inv = 1.0f / fmaxf(sqrtf(ss), 1e-12f);
  const float nx = v.x * inv, ny = v.y * inv;
  float2* dst = (float2*)(feats + (size_t)m * NN * DD + (size_t)row * DD);
  dst[t] = make_float2(nx, ny);
  __hip_bfloat16* db = fbf + (size_t)m * NN * DD + (size_t)row * DD;
  db[2 * t]     = __float2bfloat16(nx);
  db[2 * t + 1] = __float2bfloat16(ny);
}

// ---------------- K2: MFMA Gram + fused weighted-sim/exp/row-reduce ----------------
// block = 256 thr = 4 waves (2x2), block tile 64x64, wave tile 32x32 (2x2 MFMA frags)
__global__ __launch_bounds__(256) void k_sim(const __hip_bfloat16* __restrict__ fbf,
                                             float* __restrict__ rowsum,
                                             float* __restrict__ pos_e,
                                             float* __restrict__ diag_e) {
  const int tid  = threadIdx.x;
  const int lane = tid & 63;
  const int wid  = tid >> 6;            // 0..3
  const int wr   = wid >> 1, wc = wid & 1;
  const int rowBase = blockIdx.y * 64 + wr * 32;
  const int colBase = blockIdx.x * 64 + wc * 32;
  const int l15 = lane & 15;
  const int kg  = lane >> 4;            // 0..3

  f32x4 acc[3][2][2] = {};              // [modality][ti][tj], all statically indexed

  #pragma unroll
  for (int m = 0; m < 3; ++m) {
    const __hip_bfloat16* F = fbf + (size_t)m * NN * DD;
    #pragma unroll
    for (int ks = 0; ks < 4; ++ks) {    // K = 128 = 4 x 32
      const int k0 = ks * 32 + kg * 8;
      const bf16x8 a0 = *(const bf16x8*)(F + (size_t)(rowBase + 0  + l15) * DD + k0);
      const bf16x8 a1 = *(const bf16x8*)(F + (size_t)(rowBase + 16 + l15) * DD + k0);
      const bf16x8 b0 = *(const bf16x8*)(F + (size_t)(colBase + 0  + l15) * DD + k0);
      const bf16x8 b1 = *(const bf16x8*)(F + (size_t)(colBase + 16 + l15) * DD + k0);
      acc[m][0][0] = __builtin_amdgcn_mfma_f32_16x16x32_bf16(a0, b0, acc[m][0][0], 0, 0, 0);
      acc[m][0][1] = __builtin_amdgcn_mfma_f32_16x16x32_bf16(a0, b1, acc[m][0][1], 0, 0, 0);
      acc[m][1][0] = __builtin_amdgcn_mfma_f32_16x16x32_bf16(a1, b0, acc[m][1][0], 0, 0, 0);
      acc[m][1][1] = __builtin_amdgcn_mfma_f32_16x16x32_bf16(a1, b1, acc[m][1][1], 0, 0, 0);
    }
  }

  // epilogue: C/D map (verified): col = lane&15, row = (lane>>4)*4 + reg
  const float wv_[3] = {0.4f, 0.3f, 0.3f};
  #pragma unroll
  for (int ti = 0; ti < 2; ++ti) {
    #pragma unroll
    for (int j = 0; j < 4; ++j) {
      const int i = rowBase + ti * 16 + kg * 4 + j;
      float rsum = 0.f;
      #pragma unroll
      for (int tj = 0; tj < 2; ++tj) {
        const int jcol = colBase + tj * 16 + l15;
        float num = 0.f, den = 0.f;
        #pragma unroll
        for (int m = 0; m < 3; ++m) {
          const float s = acc[m][ti][tj][j];
          if (s != 0.0f) { num = fmaf(wv_[m], s, num); den += wv_[m]; }
        }
        const float wsim = num / (den + 1e-12f);
        const float e = expf(2.0f * wsim);
        rsum += e;
        if (jcol == i) diag_e[i] = e;
        if (jcol == ((i + BB) & (NN - 1))) pos_e[i] = e;
      }
      // sum across the 16 lanes of this row-group (masks < 16 stay in-group)
      #pragma unroll
      for (int msk = 8; msk >= 1; msk >>= 1) rsum += __shfl_xor(rsum, msk);
      if (l15 == 0) atomicAdd(&rowsum[i], rsum);
    }
  }
}

// ---------------- K3: prototypical logits + log-softmax CE per row ----------------
__global__ __launch_bounds__(256) void k_proto(const float* __restrict__ feats,
                                               const float* __restrict__ cst,
                                               const float* __restrict__ ccar,
                                               const float* __restrict__ cpl,
                                               const float* __restrict__ conc,
                                               const int* __restrict__ labels,
                                               float* __restrict__ lossB) {
  __shared__ float rf[3 * DD];
  __shared__ float zbuf[CC];
  __shared__ float red[4];
  const int row = blockIdx.x;
  const int tid = threadIdx.x;
  for (int t = tid; t < 3 * DD; t += 256)
    rf[t] = feats[(size_t)(t >> 7) * NN * DD + (size_t)row * DD + (t & 127)];
  __syncthreads();

  const float wgt[3] = {0.4f, 0.3f, 0.3f};
  const float* cen[3] = {cst, ccar, cpl};
  for (int c = tid; c < CC; c += 256) {
    float num = 0.f, den = 0.f;
    #pragma unroll
    for (int m = 0; m < 3; ++m) {
      const float4* cp = (const float4*)(cen[m] + (size_t)c * DD);
      const float4* rp = (const float4*)(rf + m * DD);
      float dot = 0.f;
      #pragma unroll
      for (int k = 0; k < DD / 4; ++k) {
        const float4 a = rp[k];
        const float4 b = cp[k];
        dot = fmaf(a.x, b.x, dot); dot = fmaf(a.y, b.y, dot);
        dot = fmaf(a.z, b.z, dot); dot = fmaf(a.w, b.w, dot);
      }
      const float tc = conc[m * CC + c];
      const float l = dot / (tc + 1e-12f);
      if (!(tc == 0.0f || l == 0.0f)) { num = fmaf(wgt[m], l, num); den += wgt[m]; }
    }
    zbuf[c] = num / (den + 1e-12f);
  }
  __syncthreads();

  const int lane = tid & 63;
  const int wv = tid >> 6;
  float mx = fmaxf(zbuf[tid], zbuf[tid + 256]);
  #pragma unroll
  for (int k = 32; k >= 1; k >>= 1) mx = fmaxf(mx, __shfl_xor(mx, k));
  if (lane == 0) red[wv] = mx;
  __syncthreads();
  mx = fmaxf(fmaxf(red[0], red[1]), fmaxf(red[2], red[3]));
  __syncthreads();
  float se = expf(zbuf[tid] - mx) + expf(zbuf[tid + 256] - mx);
  #pragma unroll
  for (int k = 32; k >= 1; k >>= 1) se += __shfl_xor(se, k);
  if (lane == 0) red[wv] = se;
  __syncthreads();
  if (tid == 0) {
    const float lse = mx + logf(red[0] + red[1] + red[2] + red[3]);
    lossB[row] = lse - zbuf[labels[row]];
  }
}

// ---------------- K4: final scalar reduce ----------------
__global__ void k_final(const float* __restrict__ rowsum, const float* __restrict__ pos_e,
                        const float* __restrict__ diag_e, const float* __restrict__ lossB,
                        float* __restrict__ out) {
  __shared__ float redA[4], redB[4];
  const int tid = threadIdx.x;
  float sa = 0.f, sb = 0.f;
  for (int i = tid; i < NN; i += 256) {
    sa += logf(rowsum[i] - diag_e[i]) - logf(pos_e[i]);
    sb += lossB[i];
  }
  const int lane = tid & 63, wv = tid >> 6;
  #pragma unroll
  for (int k = 32; k >= 1; k >>= 1) { sa += __shfl_xor(sa, k); sb += __shfl_xor(sb, k); }
  if (lane == 0) { redA[wv] = sa; redB[wv] = sb; }
  __syncthreads();
  if (tid == 0) {
    const float la = redA[0] + redA[1] + redA[2] + redA[3];
    const float lb = redB[0] + redB[1] + redB[2] + redB[3];
    out[0] = la / (float)NN + lb / (float)NN;
  }
}

extern "C" void kernel_launch(void* const* d_in, const int* in_sizes, int n_in,
                              void* d_out, int out_size, void* d_ws, size_t ws_size,
                              hipStream_t stream) {
  (void)in_sizes; (void)n_in; (void)out_size; (void)ws_size;
  const float* si  = (const float*)d_in[0];
  const float* sj  = (const float*)d_in[1];
  const float* ci  = (const float*)d_in[2];
  const float* cj  = (const float*)d_in[3];
  const float* pi  = (const float*)d_in[4];
  const float* pj  = (const float*)d_in[5];
  const int*   lab = (const int*)d_in[6];
  const float* cst = (const float*)d_in[7];
  const float* cca = (const float*)d_in[8];
  const float* cpl = (const float*)d_in[9];
  const float* cnc = (const float*)d_in[10];

  float* ws     = (float*)d_ws;
  float* feats  = ws;                         // 3*4096*128 fp32
  float* rowsum = ws + (size_t)3 * NN * DD;   // 4096
  float* pos_e  = rowsum + NN;                // 4096
  float* diag_e = pos_e + NN;                 // 4096
  float* lossB  = diag_e + NN;                // 4096
  __hip_bfloat16* fbf = (__hip_bfloat16*)(lossB + NN);  // 3*4096*128 bf16 (~3 MB)

  hipMemsetAsync(rowsum, 0, NN * sizeof(float), stream);

  k_norm<<<dim3(NN, 3), 64, 0, stream>>>(si, sj, ci, cj, pi, pj, feats, fbf);
  k_sim<<<dim3(NN / 64, NN / 64), 256, 0, stream>>>(fbf, rowsum, pos_e, diag_e);
  k_proto<<<NN, 256, 0, stream>>>(feats, cst, cca, cpl, cnc, lab, lossB);
  k_final<<<1, 256, 0, stream>>>(rowsum, pos_e, diag_e, lossB, (float*)d_out);
}

// Round 4
// 224.351 us; speedup vs baseline: 4.5108x; 4.5108x over previous
//
#include <hip/hip_runtime.h>
#include <hip/hip_bf16.h>
#include <math.h>

#define BB 2048   // batch per view
#define NN 4096   // 2*BB
#define DD 128    // feature dim
#define CC 512    // classes

typedef __attribute__((ext_vector_type(8))) short bf16x8;   // 8 bf16 = 4 VGPRs
typedef __attribute__((ext_vector_type(4))) float f32x4;

// ---------------- K1: l2-normalize the 6 inputs into 3 concatenated bf16 feats ----------
__global__ void k_norm(const float* __restrict__ si, const float* __restrict__ sj,
                       const float* __restrict__ ci, const float* __restrict__ cj,
                       const float* __restrict__ pi, const float* __restrict__ pj,
                       __hip_bfloat16* __restrict__ fbf) {
  const int row = blockIdx.x;   // 0..4095
  const int m   = blockIdx.y;   // 0..2
  const float* src;
  if (m == 0)      src = (row < BB) ? si : sj;
  else if (m == 1) src = (row < BB) ? ci : cj;
  else             src = (row < BB) ? pi : pj;
  const int r = (row < BB) ? row : row - BB;
  const float2* s2 = (const float2*)(src + (size_t)r * DD);
  const int t = threadIdx.x;    // 0..63
  float2 v = s2[t];
  float ss = v.x * v.x + v.y * v.y;
  #pragma unroll
  for (int k = 32; k >= 1; k >>= 1) ss += __shfl_xor(ss, k);
  const float inv = 1.0f / fmaxf(sqrtf(ss), 1e-12f);
  __hip_bfloat16* db = fbf + (size_t)m * NN * DD + (size_t)row * DD;
  db[2 * t]     = __float2bfloat16(v.x * inv);
  db[2 * t + 1] = __float2bfloat16(v.y * inv);
}

// ---------------- K1b: bf16-cast the 3 centroid matrices ----------------
__global__ void k_prep(const float* __restrict__ cst, const float* __restrict__ cca,
                       const float* __restrict__ cpl, __hip_bfloat16* __restrict__ cbf) {
  const int row = blockIdx.x;   // 0..511
  const int m   = blockIdx.y;   // 0..2
  const float* src = (m == 0) ? cst : (m == 1) ? cca : cpl;
  const float2* s2 = (const float2*)(src + (size_t)row * DD);
  const int t = threadIdx.x;    // 0..63
  float2 v = s2[t];
  __hip_bfloat16* db = cbf + (size_t)m * CC * DD + (size_t)row * DD;
  db[2 * t]     = __float2bfloat16(v.x);
  db[2 * t + 1] = __float2bfloat16(v.y);
}

// ---------------- K2: MFMA Gram + fused weighted-sim/exp/row-reduce ----------------
// block = 256 thr = 4 waves (2x2), block tile 64x64, wave tile 32x32 (2x2 MFMA frags)
__global__ __launch_bounds__(256) void k_sim(const __hip_bfloat16* __restrict__ fbf,
                                             float* __restrict__ rowsum,
                                             float* __restrict__ pos_e,
                                             float* __restrict__ diag_e) {
  const int tid  = threadIdx.x;
  const int lane = tid & 63;
  const int wid  = tid >> 6;            // 0..3
  const int wr   = wid >> 1, wc = wid & 1;
  const int rowBase = blockIdx.y * 64 + wr * 32;
  const int colBase = blockIdx.x * 64 + wc * 32;
  const int l15 = lane & 15;
  const int kg  = lane >> 4;            // 0..3

  f32x4 acc[3][2][2] = {};              // [modality][ti][tj], all statically indexed

  #pragma unroll
  for (int m = 0; m < 3; ++m) {
    const __hip_bfloat16* F = fbf + (size_t)m * NN * DD;
    #pragma unroll
    for (int ks = 0; ks < 4; ++ks) {    // K = 128 = 4 x 32
      const int k0 = ks * 32 + kg * 8;
      const bf16x8 a0 = *(const bf16x8*)(F + (size_t)(rowBase + 0  + l15) * DD + k0);
      const bf16x8 a1 = *(const bf16x8*)(F + (size_t)(rowBase + 16 + l15) * DD + k0);
      const bf16x8 b0 = *(const bf16x8*)(F + (size_t)(colBase + 0  + l15) * DD + k0);
      const bf16x8 b1 = *(const bf16x8*)(F + (size_t)(colBase + 16 + l15) * DD + k0);
      acc[m][0][0] = __builtin_amdgcn_mfma_f32_16x16x32_bf16(a0, b0, acc[m][0][0], 0, 0, 0);
      acc[m][0][1] = __builtin_amdgcn_mfma_f32_16x16x32_bf16(a0, b1, acc[m][0][1], 0, 0, 0);
      acc[m][1][0] = __builtin_amdgcn_mfma_f32_16x16x32_bf16(a1, b0, acc[m][1][0], 0, 0, 0);
      acc[m][1][1] = __builtin_amdgcn_mfma_f32_16x16x32_bf16(a1, b1, acc[m][1][1], 0, 0, 0);
    }
  }

  // epilogue: C/D map (verified): col = lane&15, row = (lane>>4)*4 + reg
  const float wv_[3] = {0.4f, 0.3f, 0.3f};
  #pragma unroll
  for (int ti = 0; ti < 2; ++ti) {
    #pragma unroll
    for (int j = 0; j < 4; ++j) {
      const int i = rowBase + ti * 16 + kg * 4 + j;
      float rsum = 0.f;
      #pragma unroll
      for (int tj = 0; tj < 2; ++tj) {
        const int jcol = colBase + tj * 16 + l15;
        float num = 0.f, den = 0.f;
        #pragma unroll
        for (int m = 0; m < 3; ++m) {
          const float s = acc[m][ti][tj][j];
          if (s != 0.0f) { num = fmaf(wv_[m], s, num); den += wv_[m]; }
        }
        const float wsim = num / (den + 1e-12f);
        const float e = expf(2.0f * wsim);
        rsum += e;
        if (jcol == i) diag_e[i] = e;
        if (jcol == ((i + BB) & (NN - 1))) pos_e[i] = e;
      }
      // sum across the 16 lanes of this row-group (masks < 16 stay in-group)
      #pragma unroll
      for (int msk = 8; msk >= 1; msk >>= 1) rsum += __shfl_xor(rsum, msk);
      if (l15 == 0) atomicAdd(&rowsum[i], rsum);
    }
  }
}

// ---------------- K3a: proto logits GEMM (rows [rowOff, rowOff+2048) ) ----------------
// Z[r - rowOff][c] = weighted/masked logit; same tile structure as k_sim.
__global__ __launch_bounds__(256) void k_pmm(const __hip_bfloat16* __restrict__ fbf,
                                             const __hip_bfloat16* __restrict__ cbf,
                                             const float* __restrict__ conc,
                                             float* __restrict__ Z, int rowOff) {
  const int tid  = threadIdx.x;
  const int lane = tid & 63;
  const int wid  = tid >> 6;
  const int wr   = wid >> 1, wc = wid & 1;
  const int rowBase = rowOff + blockIdx.y * 64 + wr * 32;  // feature row
  const int colBase = blockIdx.x * 64 + wc * 32;           // class
  const int l15 = lane & 15;
  const int kg  = lane >> 4;

  f32x4 acc[3][2][2] = {};

  #pragma unroll
  for (int m = 0; m < 3; ++m) {
    const __hip_bfloat16* F = fbf + (size_t)m * NN * DD;
    const __hip_bfloat16* Cm = cbf + (size_t)m * CC * DD;
    #pragma unroll
    for (int ks = 0; ks < 4; ++ks) {
      const int k0 = ks * 32 + kg * 8;
      const bf16x8 a0 = *(const bf16x8*)(F  + (size_t)(rowBase + 0  + l15) * DD + k0);
      const bf16x8 a1 = *(const bf16x8*)(F  + (size_t)(rowBase + 16 + l15) * DD + k0);
      const bf16x8 b0 = *(const bf16x8*)(Cm + (size_t)(colBase + 0  + l15) * DD + k0);
      const bf16x8 b1 = *(const bf16x8*)(Cm + (size_t)(colBase + 16 + l15) * DD + k0);
      acc[m][0][0] = __builtin_amdgcn_mfma_f32_16x16x32_bf16(a0, b0, acc[m][0][0], 0, 0, 0);
      acc[m][0][1] = __builtin_amdgcn_mfma_f32_16x16x32_bf16(a0, b1, acc[m][0][1], 0, 0, 0);
      acc[m][1][0] = __builtin_amdgcn_mfma_f32_16x16x32_bf16(a1, b0, acc[m][1][0], 0, 0, 0);
      acc[m][1][1] = __builtin_amdgcn_mfma_f32_16x16x32_bf16(a1, b1, acc[m][1][1], 0, 0, 0);
    }
  }

  const float wv_[3] = {0.4f, 0.3f, 0.3f};
  #pragma unroll
  for (int ti = 0; ti < 2; ++ti) {
    #pragma unroll
    for (int j = 0; j < 4; ++j) {
      const int r = rowBase + ti * 16 + kg * 4 + j - rowOff;   // local row in Z
      #pragma unroll
      for (int tj = 0; tj < 2; ++tj) {
        const int c = colBase + tj * 16 + l15;
        float num = 0.f, den = 0.f;
        #pragma unroll
        for (int m = 0; m < 3; ++m) {
          const float dot = acc[m][ti][tj][j];
          const float tc  = conc[m * CC + c];
          const float l   = dot / (tc + 1e-12f);
          if (!(tc == 0.0f || l == 0.0f)) { num = fmaf(wv_[m], l, num); den += wv_[m]; }
        }
        Z[(size_t)r * CC + c] = num / (den + 1e-12f);
      }
    }
  }
}

// ---------------- K3b: per-row lse - z_label (one wave per row) ----------------
__global__ __launch_bounds__(256) void k_smax(const float* __restrict__ Z,
                                              const int* __restrict__ labels,
                                              float* __restrict__ lossB, int rowOff) {
  const int tid  = threadIdx.x;
  const int lane = tid & 63;
  const int rloc = blockIdx.x * 4 + (tid >> 6);   // local row 0..2047
  const int row  = rowOff + rloc;
  const float4* zr = (const float4*)(Z + (size_t)rloc * CC);
  const float4 a = zr[lane * 2];
  const float4 b = zr[lane * 2 + 1];
  float mx = fmaxf(fmaxf(fmaxf(a.x, a.y), fmaxf(a.z, a.w)),
                   fmaxf(fmaxf(b.x, b.y), fmaxf(b.z, b.w)));
  #pragma unroll
  for (int k = 32; k >= 1; k >>= 1) mx = fmaxf(mx, __shfl_xor(mx, k));
  float se = expf(a.x - mx) + expf(a.y - mx) + expf(a.z - mx) + expf(a.w - mx)
           + expf(b.x - mx) + expf(b.y - mx) + expf(b.z - mx) + expf(b.w - mx);
  #pragma unroll
  for (int k = 32; k >= 1; k >>= 1) se += __shfl_xor(se, k);
  if (lane == 0) {
    const float zlab = Z[(size_t)rloc * CC + labels[row]];
    lossB[row] = mx + logf(se) - zlab;
  }
}

// ---------------- K4: final scalar reduce ----------------
__global__ void k_final(const float* __restrict__ rowsum, const float* __restrict__ pos_e,
                        const float* __restrict__ diag_e, const float* __restrict__ lossB,
                        float* __restrict__ out) {
  __shared__ float redA[4], redB[4];
  const int tid = threadIdx.x;
  float sa = 0.f, sb = 0.f;
  for (int i = tid; i < NN; i += 256) {
    sa += logf(rowsum[i] - diag_e[i]) - logf(pos_e[i]);
    sb += lossB[i];
  }
  const int lane = tid & 63, wv = tid >> 6;
  #pragma unroll
  for (int k = 32; k >= 1; k >>= 1) { sa += __shfl_xor(sa, k); sb += __shfl_xor(sb, k); }
  if (lane == 0) { redA[wv] = sa; redB[wv] = sb; }
  __syncthreads();
  if (tid == 0) {
    const float la = redA[0] + redA[1] + redA[2] + redA[3];
    const float lb = redB[0] + redB[1] + redB[2] + redB[3];
    out[0] = la / (float)NN + lb / (float)NN;
  }
}

extern "C" void kernel_launch(void* const* d_in, const int* in_sizes, int n_in,
                              void* d_out, int out_size, void* d_ws, size_t ws_size,
                              hipStream_t stream) {
  (void)in_sizes; (void)n_in; (void)out_size; (void)ws_size;
  const float* si  = (const float*)d_in[0];
  const float* sj  = (const float*)d_in[1];
  const float* ci  = (const float*)d_in[2];
  const float* cj  = (const float*)d_in[3];
  const float* pi  = (const float*)d_in[4];
  const float* pj  = (const float*)d_in[5];
  const int*   lab = (const int*)d_in[6];
  const float* cst = (const float*)d_in[7];
  const float* cca = (const float*)d_in[8];
  const float* cpl = (const float*)d_in[9];
  const float* cnc = (const float*)d_in[10];

  // ws layout (proven bound ws_size >= 9.47 MB; this uses ~7.8 MB):
  float* ws     = (float*)d_ws;
  float* Z      = ws;                          // 2048*512 f32 = 4 MB (reused per half)
  float* rowsum = Z + (size_t)BB * CC;         // 4096
  float* pos_e  = rowsum + NN;                 // 4096
  float* diag_e = pos_e + NN;                  // 4096
  float* lossB  = diag_e + NN;                 // 4096
  __hip_bfloat16* fbf = (__hip_bfloat16*)(lossB + NN);          // 3*4096*128 bf16 = 3 MB
  __hip_bfloat16* cbf = fbf + (size_t)3 * NN * DD;              // 3*512*128 bf16 = 384 KB

  hipMemsetAsync(rowsum, 0, NN * sizeof(float), stream);

  k_norm<<<dim3(NN, 3), 64, 0, stream>>>(si, sj, ci, cj, pi, pj, fbf);
  k_prep<<<dim3(CC, 3), 64, 0, stream>>>(cst, cca, cpl, cbf);
  k_sim<<<dim3(NN / 64, NN / 64), 256, 0, stream>>>(fbf, rowsum, pos_e, diag_e);
  // proto loss in two half-batches, reusing Z
  k_pmm<<<dim3(CC / 64, BB / 64), 256, 0, stream>>>(fbf, cbf, cnc, Z, 0);
  k_smax<<<BB / 4, 256, 0, stream>>>(Z, lab, lossB, 0);
  k_pmm<<<dim3(CC / 64, BB / 64), 256, 0, stream>>>(fbf, cbf, cnc, Z, BB);
  k_smax<<<BB / 4, 256, 0, stream>>>(Z, lab, lossB, BB);
  k_final<<<1, 256, 0, stream>>>(rowsum, pos_e, diag_e, lossB, (float*)d_out);
}

// Round 5
// 170.475 us; speedup vs baseline: 5.9364x; 1.3160x over previous
//
#include <hip/hip_runtime.h>
#include <hip/hip_bf16.h>
#include <math.h>

#define BB 2048   // batch per view
#define NN 4096   // 2*BB
#define DD 128    // feature dim per modality
#define KK 384    // 3*DD concat reduction
#define CC 512    // classes

typedef __attribute__((ext_vector_type(8))) short bf16x8;   // 8 bf16 = 4 VGPRs
typedef __attribute__((ext_vector_type(4))) float f32x4;

// ---------------- K1: l2-normalize + fold sqrt(w_m); bf16 feats [m][row][128] ----------
__global__ void k_norm(const float* __restrict__ si, const float* __restrict__ sj,
                       const float* __restrict__ ci, const float* __restrict__ cj,
                       const float* __restrict__ pi, const float* __restrict__ pj,
                       __hip_bfloat16* __restrict__ fbf) {
  const int row = blockIdx.x;   // 0..4095
  const int m   = blockIdx.y;   // 0..2
  const float* src;
  float sqw;
  if (m == 0)      { src = (row < BB) ? si : sj; sqw = 0.632455532033676f; }   // sqrt(.4)
  else if (m == 1) { src = (row < BB) ? ci : cj; sqw = 0.547722557505166f; }   // sqrt(.3)
  else             { src = (row < BB) ? pi : pj; sqw = 0.547722557505166f; }
  const int r = (row < BB) ? row : row - BB;
  const float2* s2 = (const float2*)(src + (size_t)r * DD);
  const int t = threadIdx.x;    // 0..63
  float2 v = s2[t];
  float ss = v.x * v.x + v.y * v.y;
  #pragma unroll
  for (int k = 32; k >= 1; k >>= 1) ss += __shfl_xor(ss, k);
  const float inv = sqw / fmaxf(sqrtf(ss), 1e-12f);
  __hip_bfloat16* db = fbf + (size_t)m * NN * DD + (size_t)row * DD;
  db[2 * t]     = __float2bfloat16(v.x * inv);
  db[2 * t + 1] = __float2bfloat16(v.y * inv);
}

// ---------------- K1b: centroids scaled by sqrt(w_m)/(conc+1e-12), bf16 ----------------
__global__ void k_prep(const float* __restrict__ cst, const float* __restrict__ cca,
                       const float* __restrict__ cpl, const float* __restrict__ conc,
                       __hip_bfloat16* __restrict__ cbf) {
  const int row = blockIdx.x;   // class 0..511
  const int m   = blockIdx.y;   // 0..2
  const float* src = (m == 0) ? cst : (m == 1) ? cca : cpl;
  const float sqw = (m == 0) ? 0.632455532033676f : 0.547722557505166f;
  const float sc  = sqw / (conc[m * CC + row] + 1e-12f);
  const float2* s2 = (const float2*)(src + (size_t)row * DD);
  const int t = threadIdx.x;    // 0..63
  float2 v = s2[t];
  __hip_bfloat16* db = cbf + (size_t)m * CC * DD + (size_t)row * DD;
  db[2 * t]     = __float2bfloat16(v.x * sc);
  db[2 * t + 1] = __float2bfloat16(v.y * sc);
}

// ---------------- K2: single K=384 Gram via MFMA + fused exp/row-reduce ----------------
// block 256 = 4 waves (2x2), block tile 128x128, wave tile 64x64 (4x4 frags of 16x16)
__global__ __launch_bounds__(256) void k_sim(const __hip_bfloat16* __restrict__ fbf,
                                             float* __restrict__ rowsum,
                                             float* __restrict__ pos_e,
                                             float* __restrict__ diag_e) {
  const int tid  = threadIdx.x;
  const int lane = tid & 63;
  const int wid  = tid >> 6;
  const int wr   = wid >> 1, wc = wid & 1;
  const int rowBase = blockIdx.y * 128 + wr * 64;
  const int colBase = blockIdx.x * 128 + wc * 64;
  const int l15 = lane & 15;
  const int kg  = lane >> 4;            // 0..3

  f32x4 acc[4][4] = {};                 // [ti][tj] — static indices only

  #pragma unroll
  for (int ks = 0; ks < 12; ++ks) {     // K = 384 = 12 x 32 (modality = ks>>2)
    const __hip_bfloat16* F = fbf + (size_t)(ks >> 2) * NN * DD + ((ks & 3) * 32 + kg * 8);
    bf16x8 af[4], bf_[4];
    #pragma unroll
    for (int ti = 0; ti < 4; ++ti)
      af[ti] = *(const bf16x8*)(F + (size_t)(rowBase + ti * 16 + l15) * DD);
    #pragma unroll
    for (int tj = 0; tj < 4; ++tj)
      bf_[tj] = *(const bf16x8*)(F + (size_t)(colBase + tj * 16 + l15) * DD);
    #pragma unroll
    for (int ti = 0; ti < 4; ++ti)
      #pragma unroll
      for (int tj = 0; tj < 4; ++tj)
        acc[ti][tj] = __builtin_amdgcn_mfma_f32_16x16x32_bf16(af[ti], bf_[tj], acc[ti][tj], 0, 0, 0);
  }

  // epilogue: C/D map: col = colBase + tj*16 + (lane&15), row = rowBase + ti*16 + (lane>>4)*4 + reg
  #pragma unroll
  for (int ti = 0; ti < 4; ++ti) {
    #pragma unroll
    for (int j = 0; j < 4; ++j) {
      const int i = rowBase + ti * 16 + kg * 4 + j;
      float rsum = 0.f;
      #pragma unroll
      for (int tj = 0; tj < 4; ++tj) {
        const int jcol = colBase + tj * 16 + l15;
        const float e = expf(2.0f * acc[ti][tj][j]);   // den == 1 (weights folded)
        rsum += e;
        if (jcol == i) diag_e[i] = e;
        if (jcol == ((i + BB) & (NN - 1))) pos_e[i] = e;
      }
      #pragma unroll
      for (int msk = 8; msk >= 1; msk >>= 1) rsum += __shfl_xor(rsum, msk);
      if (l15 == 0) atomicAdd(&rowsum[i], rsum);
    }
  }
}

// ---------------- K3a: proto logits GEMM, K=384, rows [rowOff, rowOff+2048) ----------
// block 64x64 (4 waves 2x2, wave 32x32)
__global__ __launch_bounds__(256) void k_pmm(const __hip_bfloat16* __restrict__ fbf,
                                             const __hip_bfloat16* __restrict__ cbf,
                                             float* __restrict__ Z, int rowOff) {
  const int tid  = threadIdx.x;
  const int lane = tid & 63;
  const int wid  = tid >> 6;
  const int wr   = wid >> 1, wc = wid & 1;
  const int rowBase = rowOff + blockIdx.y * 64 + wr * 32;
  const int colBase = blockIdx.x * 64 + wc * 32;
  const int l15 = lane & 15;
  const int kg  = lane >> 4;

  f32x4 acc[2][2] = {};

  #pragma unroll
  for (int ks = 0; ks < 12; ++ks) {
    const int koff = (ks & 3) * 32 + kg * 8;
    const __hip_bfloat16* F  = fbf + (size_t)(ks >> 2) * NN * DD + koff;
    const __hip_bfloat16* Cm = cbf + (size_t)(ks >> 2) * CC * DD + koff;
    bf16x8 af[2], bf_[2];
    #pragma unroll
    for (int ti = 0; ti < 2; ++ti)
      af[ti] = *(const bf16x8*)(F + (size_t)(rowBase + ti * 16 + l15) * DD);
    #pragma unroll
    for (int tj = 0; tj < 2; ++tj)
      bf_[tj] = *(const bf16x8*)(Cm + (size_t)(colBase + tj * 16 + l15) * DD);
    #pragma unroll
    for (int ti = 0; ti < 2; ++ti)
      #pragma unroll
      for (int tj = 0; tj < 2; ++tj)
        acc[ti][tj] = __builtin_amdgcn_mfma_f32_16x16x32_bf16(af[ti], bf_[tj], acc[ti][tj], 0, 0, 0);
  }

  #pragma unroll
  for (int ti = 0; ti < 2; ++ti) {
    #pragma unroll
    for (int j = 0; j < 4; ++j) {
      const int r = rowBase + ti * 16 + kg * 4 + j - rowOff;   // local row in Z
      #pragma unroll
      for (int tj = 0; tj < 2; ++tj) {
        const int c = colBase + tj * 16 + l15;
        Z[(size_t)r * CC + c] = acc[ti][tj][j];                // den == 1 (weights folded)
      }
    }
  }
}

// ---------------- K3b: per-row lse - z_label (one wave per row) ----------------
__global__ __launch_bounds__(256) void k_smax(const float* __restrict__ Z,
                                              const int* __restrict__ labels,
                                              float* __restrict__ lossB, int rowOff) {
  const int tid  = threadIdx.x;
  const int lane = tid & 63;
  const int rloc = blockIdx.x * 4 + (tid >> 6);   // local row 0..2047
  const int row  = rowOff + rloc;
  const float4* zr = (const float4*)(Z + (size_t)rloc * CC);
  const float4 a = zr[lane * 2];
  const float4 b = zr[lane * 2 + 1];
  float mx = fmaxf(fmaxf(fmaxf(a.x, a.y), fmaxf(a.z, a.w)),
                   fmaxf(fmaxf(b.x, b.y), fmaxf(b.z, b.w)));
  #pragma unroll
  for (int k = 32; k >= 1; k >>= 1) mx = fmaxf(mx, __shfl_xor(mx, k));
  float se = expf(a.x - mx) + expf(a.y - mx) + expf(a.z - mx) + expf(a.w - mx)
           + expf(b.x - mx) + expf(b.y - mx) + expf(b.z - mx) + expf(b.w - mx);
  #pragma unroll
  for (int k = 32; k >= 1; k >>= 1) se += __shfl_xor(se, k);
  if (lane == 0) {
    const float zlab = Z[(size_t)rloc * CC + labels[row]];
    lossB[row] = mx + logf(se) - zlab;
  }
}

// ---------------- K4: final scalar reduce ----------------
__global__ void k_final(const float* __restrict__ rowsum, const float* __restrict__ pos_e,
                        const float* __restrict__ diag_e, const float* __restrict__ lossB,
                        float* __restrict__ out) {
  __shared__ float redA[4], redB[4];
  const int tid = threadIdx.x;
  float sa = 0.f, sb = 0.f;
  for (int i = tid; i < NN; i += 256) {
    sa += logf(rowsum[i] - diag_e[i]) - logf(pos_e[i]);
    sb += lossB[i];
  }
  const int lane = tid & 63, wv = tid >> 6;
  #pragma unroll
  for (int k = 32; k >= 1; k >>= 1) { sa += __shfl_xor(sa, k); sb += __shfl_xor(sb, k); }
  if (lane == 0) { redA[wv] = sa; redB[wv] = sb; }
  __syncthreads();
  if (tid == 0) {
    const float la = redA[0] + redA[1] + redA[2] + redA[3];
    const float lb = redB[0] + redB[1] + redB[2] + redB[3];
    out[0] = la / (float)NN + lb / (float)NN;
  }
}

extern "C" void kernel_launch(void* const* d_in, const int* in_sizes, int n_in,
                              void* d_out, int out_size, void* d_ws, size_t ws_size,
                              hipStream_t stream) {
  (void)in_sizes; (void)n_in; (void)out_size; (void)ws_size;
  const float* si  = (const float*)d_in[0];
  const float* sj  = (const float*)d_in[1];
  const float* ci  = (const float*)d_in[2];
  const float* cj  = (const float*)d_in[3];
  const float* pi  = (const float*)d_in[4];
  const float* pj  = (const float*)d_in[5];
  const int*   lab = (const int*)d_in[6];
  const float* cst = (const float*)d_in[7];
  const float* cca = (const float*)d_in[8];
  const float* cpl = (const float*)d_in[9];
  const float* cnc = (const float*)d_in[10];

  // ws layout (~7.45 MB of the >=9.47 MB proven budget):
  float* ws     = (float*)d_ws;
  float* Z      = ws;                          // 2048*512 f32 = 4 MB (reused per half)
  float* rowsum = Z + (size_t)BB * CC;         // 4096
  float* pos_e  = rowsum + NN;                 // 4096
  float* diag_e = pos_e + NN;                  // 4096
  float* lossB  = diag_e + NN;                 // 4096
  __hip_bfloat16* fbf = (__hip_bfloat16*)(lossB + NN);          // 3*4096*128 bf16 = 3 MB
  __hip_bfloat16* cbf = fbf + (size_t)3 * NN * DD;              // 3*512*128 bf16 = 384 KB

  hipMemsetAsync(rowsum, 0, NN * sizeof(float), stream);

  k_norm<<<dim3(NN, 3), 64, 0, stream>>>(si, sj, ci, cj, pi, pj, fbf);
  k_prep<<<dim3(CC, 3), 64, 0, stream>>>(cst, cca, cpl, cnc, cbf);
  k_sim<<<dim3(NN / 128, NN / 128), 256, 0, stream>>>(fbf, rowsum, pos_e, diag_e);
  // proto loss in two half-batches, reusing Z
  k_pmm<<<dim3(CC / 64, BB / 64), 256, 0, stream>>>(fbf, cbf, Z, 0);
  k_smax<<<BB / 4, 256, 0, stream>>>(Z, lab, lossB, 0);
  k_pmm<<<dim3(CC / 64, BB / 64), 256, 0, stream>>>(fbf, cbf, Z, BB);
  k_smax<<<BB / 4, 256, 0, stream>>>(Z, lab, lossB, BB);
  k_final<<<1, 256, 0, stream>>>(rowsum, pos_e, diag_e, lossB, (float*)d_out);
}

// Round 6
// 134.246 us; speedup vs baseline: 7.5384x; 1.2699x over previous
//
#include <hip/hip_runtime.h>
#include <hip/hip_bf16.h>
#include <math.h>

#define BB 2048   // batch per view
#define NN 4096   // 2*BB
#define DD 128    // feature dim per modality
#define CC 512    // classes

typedef __attribute__((ext_vector_type(8))) short bf16x8;   // 8 bf16 = 4 VGPRs
typedef __attribute__((ext_vector_type(4))) float f32x4;

// ---------------- K1: l2-normalize + fold sqrt(w_m); bf16 feats [m][row][128] ----------
__global__ void k_norm(const float* __restrict__ si, const float* __restrict__ sj,
                       const float* __restrict__ ci, const float* __restrict__ cj,
                       const float* __restrict__ pi, const float* __restrict__ pj,
                       __hip_bfloat16* __restrict__ fbf) {
  const int row = blockIdx.x;   // 0..4095
  const int m   = blockIdx.y;   // 0..2
  const float* src;
  float sqw;
  if (m == 0)      { src = (row < BB) ? si : sj; sqw = 0.632455532033676f; }   // sqrt(.4)
  else if (m == 1) { src = (row < BB) ? ci : cj; sqw = 0.547722557505166f; }   // sqrt(.3)
  else             { src = (row < BB) ? pi : pj; sqw = 0.547722557505166f; }
  const int r = (row < BB) ? row : row - BB;
  const float2* s2 = (const float2*)(src + (size_t)r * DD);
  const int t = threadIdx.x;    // 0..63
  float2 v = s2[t];
  float ss = v.x * v.x + v.y * v.y;
  #pragma unroll
  for (int k = 32; k >= 1; k >>= 1) ss += __shfl_xor(ss, k);
  const float inv = sqw / fmaxf(sqrtf(ss), 1e-12f);
  __hip_bfloat16* db = fbf + (size_t)m * NN * DD + (size_t)row * DD;
  db[2 * t]     = __float2bfloat16(v.x * inv);
  db[2 * t + 1] = __float2bfloat16(v.y * inv);
}

// ---------------- K1b: centroids scaled by sqrt(w_m)/(conc+1e-12), bf16 ----------------
__global__ void k_prep(const float* __restrict__ cst, const float* __restrict__ cca,
                       const float* __restrict__ cpl, const float* __restrict__ conc,
                       __hip_bfloat16* __restrict__ cbf) {
  const int row = blockIdx.x;   // class 0..511
  const int m   = blockIdx.y;   // 0..2
  const float* src = (m == 0) ? cst : (m == 1) ? cca : cpl;
  const float sqw = (m == 0) ? 0.632455532033676f : 0.547722557505166f;
  const float sc  = sqw / (conc[m * CC + row] + 1e-12f);
  const float2* s2 = (const float2*)(src + (size_t)row * DD);
  const int t = threadIdx.x;    // 0..63
  float2 v = s2[t];
  __hip_bfloat16* db = cbf + (size_t)m * CC * DD + (size_t)row * DD;
  db[2 * t]     = __float2bfloat16(v.x * sc);
  db[2 * t + 1] = __float2bfloat16(v.y * sc);
}

// ---------------- K2: symmetric K=384 Gram, LDS-staged, fused exp/row+col reduce -------
// Grid: 528 upper-triangle 128x128 tiles. Block 256 thr = 4 waves (2x2), wave 64x64.
// LDS tiles [128 rows][8 chunks of 16B] with chunk ^= (row&7) swizzle (2-way = free).
__global__ __launch_bounds__(256, 3) void k_sim(const __hip_bfloat16* __restrict__ fbf,
                                                float* __restrict__ rowsum,
                                                float* __restrict__ pos_e,
                                                float* __restrict__ diag_e) {
  __shared__ bf16x8 As[1024];   // 16 KB
  __shared__ bf16x8 Bs[1024];   // 16 KB

  // upper-triangle decode: blockIdx.x -> (by, bx), by <= bx
  int tB = blockIdx.x;
  int by = 0;
  while (tB >= 32 - by) { tB -= 32 - by; ++by; }
  const int bx = by + tB;
  const bool diag = (by == bx);
  const int rowBase = by * 128;
  const int colBase = bx * 128;

  const int tid  = threadIdx.x;
  const int lane = tid & 63;
  const int wid  = tid >> 6;
  const int wr   = wid >> 1, wc = wid & 1;
  const int l15  = lane & 15;
  const int kg   = lane >> 4;          // 0..3

  // staging map: thread -> (row = q*32 + (tid>>3), chunk kc = tid&7)
  const int srow = tid >> 3;           // 0..31
  const int kc   = tid & 7;
  const int sc   = kc ^ (srow & 7);    // swizzled chunk (q*32 doesn't change row&7)

  f32x4 acc[4][4] = {};
  bf16x8 ra[4], rb[4];

  // prologue: issue global loads for K-step t=0 (modality 0, koff 0)
  {
    const __hip_bfloat16* F = fbf;
    #pragma unroll
    for (int q = 0; q < 4; ++q) {
      ra[q] = *(const bf16x8*)(F + (size_t)(rowBase + q * 32 + srow) * DD + kc * 8);
      if (!diag)
        rb[q] = *(const bf16x8*)(F + (size_t)(colBase + q * 32 + srow) * DD + kc * 8);
    }
  }

  for (int t = 0; t < 6; ++t) {        // K = 384 = 6 x BK64
    // write staged regs to LDS (swizzled)
    #pragma unroll
    for (int q = 0; q < 4; ++q) {
      As[(q * 32 + srow) * 8 + sc] = ra[q];
      if (!diag) Bs[(q * 32 + srow) * 8 + sc] = rb[q];
    }
    __syncthreads();

    // issue next step's global loads (overlap with compute below)
    if (t < 5) {
      const __hip_bfloat16* F = fbf + (size_t)((t + 1) >> 1) * NN * DD + ((t + 1) & 1) * 64;
      #pragma unroll
      for (int q = 0; q < 4; ++q) {
        ra[q] = *(const bf16x8*)(F + (size_t)(rowBase + q * 32 + srow) * DD + kc * 8);
        if (!diag)
          rb[q] = *(const bf16x8*)(F + (size_t)(colBase + q * 32 + srow) * DD + kc * 8);
      }
    }

    // compute BK=64 = 2 MFMA k-slots from LDS
    const bf16x8* Bsrc = diag ? As : Bs;
    #pragma unroll
    for (int ks2 = 0; ks2 < 2; ++ks2) {
      bf16x8 a[4], b[4];
      const int ch = (ks2 * 4 + kg) ^ (l15 & 7);
      #pragma unroll
      for (int ti = 0; ti < 4; ++ti)
        a[ti] = As[(wr * 64 + ti * 16 + l15) * 8 + ch];
      #pragma unroll
      for (int tj = 0; tj < 4; ++tj)
        b[tj] = Bsrc[(wc * 64 + tj * 16 + l15) * 8 + ch];
      #pragma unroll
      for (int ti = 0; ti < 4; ++ti)
        #pragma unroll
        for (int tj = 0; tj < 4; ++tj)
          acc[ti][tj] = __builtin_amdgcn_mfma_f32_16x16x32_bf16(a[ti], b[tj], acc[ti][tj], 0, 0, 0);
    }
    __syncthreads();                   // LDS consumed; safe to overwrite next iter
  }

  // epilogue: C/D map col = base + tj*16 + l15, row = base + ti*16 + kg*4 + reg
  float csum[4] = {0.f, 0.f, 0.f, 0.f};
  #pragma unroll
  for (int ti = 0; ti < 4; ++ti) {
    #pragma unroll
    for (int j = 0; j < 4; ++j) {
      const int i = rowBase + wr * 64 + ti * 16 + kg * 4 + j;
      float rsum = 0.f;
      #pragma unroll
      for (int tj = 0; tj < 4; ++tj) {
        const int jcol = colBase + wc * 64 + tj * 16 + l15;
        const float e = expf(2.0f * acc[ti][tj][j]);
        rsum += e;
        csum[tj] += e;
        if (diag) {
          if (jcol == i) diag_e[i] = e;
        } else if (jcol == ((i + BB) & (NN - 1))) {
          pos_e[i] = e;          // pos pair is mutual: (i+BB)+BB == i (mod NN)
          pos_e[jcol] = e;
        }
      }
      #pragma unroll
      for (int msk = 8; msk >= 1; msk >>= 1) rsum += __shfl_xor(rsum, msk);
      if (l15 == 0) atomicAdd(&rowsum[i], rsum);
    }
  }
  if (!diag) {   // transposed contribution: column sums -> rowsum of column indices
    #pragma unroll
    for (int tj = 0; tj < 4; ++tj) {
      float v = csum[tj];
      v += __shfl_xor(v, 16);
      v += __shfl_xor(v, 32);
      if (lane < 16) atomicAdd(&rowsum[colBase + wc * 64 + tj * 16 + l15], v);
    }
  }
}

// ---------------- K3a: proto logits GEMM, K=384, rows [rowOff, rowOff+2048) ----------
// block 64x64 (4 waves 2x2, wave 32x32), double-buffered fragment prefetch
__global__ __launch_bounds__(256) void k_pmm(const __hip_bfloat16* __restrict__ fbf,
                                             const __hip_bfloat16* __restrict__ cbf,
                                             float* __restrict__ Z, int rowOff) {
  const int tid  = threadIdx.x;
  const int lane = tid & 63;
  const int wid  = tid >> 6;
  const int wr   = wid >> 1, wc = wid & 1;
  const int rowBase = rowOff + blockIdx.y * 64 + wr * 32;
  const int colBase = blockIdx.x * 64 + wc * 32;
  const int l15 = lane & 15;
  const int kg  = lane >> 4;

  f32x4 acc[2][2] = {};
  bf16x8 abuf[2][2], bbuf[2][2];       // [parity][ti] — static under full unroll

  {
    const int koff = kg * 8;
    #pragma unroll
    for (int ti = 0; ti < 2; ++ti) {
      abuf[0][ti] = *(const bf16x8*)(fbf + (size_t)(rowBase + ti * 16 + l15) * DD + koff);
      bbuf[0][ti] = *(const bf16x8*)(cbf + (size_t)(colBase + ti * 16 + l15) * DD + koff);
    }
  }
  #pragma unroll
  for (int ks = 0; ks < 12; ++ks) {
    const int cur = ks & 1, nxt = cur ^ 1;
    if (ks < 11) {
      const int k1 = ks + 1;
      const int koff = (k1 & 3) * 32 + kg * 8;
      const __hip_bfloat16* F  = fbf + (size_t)(k1 >> 2) * NN * DD + koff;
      const __hip_bfloat16* Cm = cbf + (size_t)(k1 >> 2) * CC * DD + koff;
      #pragma unroll
      for (int ti = 0; ti < 2; ++ti) {
        abuf[nxt][ti] = *(const bf16x8*)(F  + (size_t)(rowBase + ti * 16 + l15) * DD);
        bbuf[nxt][ti] = *(const bf16x8*)(Cm + (size_t)(colBase + ti * 16 + l15) * DD);
      }
    }
    #pragma unroll
    for (int ti = 0; ti < 2; ++ti)
      #pragma unroll
      for (int tj = 0; tj < 2; ++tj)
        acc[ti][tj] = __builtin_amdgcn_mfma_f32_16x16x32_bf16(abuf[cur][ti], bbuf[cur][tj], acc[ti][tj], 0, 0, 0);
  }

  #pragma unroll
  for (int ti = 0; ti < 2; ++ti) {
    #pragma unroll
    for (int j = 0; j < 4; ++j) {
      const int r = rowBase + ti * 16 + kg * 4 + j - rowOff;   // local row in Z
      #pragma unroll
      for (int tj = 0; tj < 2; ++tj) {
        const int c = colBase + tj * 16 + l15;
        Z[(size_t)r * CC + c] = acc[ti][tj][j];                // den == 1 (weights folded)
      }
    }
  }
}

// ---------------- K3b: per-row lse - z_label (one wave per row) ----------------
__global__ __launch_bounds__(256) void k_smax(const float* __restrict__ Z,
                                              const int* __restrict__ labels,
                                              float* __restrict__ lossB, int rowOff) {
  const int tid  = threadIdx.x;
  const int lane = tid & 63;
  const int rloc = blockIdx.x * 4 + (tid >> 6);   // local row 0..2047
  const int row  = rowOff + rloc;
  const float4* zr = (const float4*)(Z + (size_t)rloc * CC);
  const float4 a = zr[lane * 2];
  const float4 b = zr[lane * 2 + 1];
  float mx = fmaxf(fmaxf(fmaxf(a.x, a.y), fmaxf(a.z, a.w)),
                   fmaxf(fmaxf(b.x, b.y), fmaxf(b.z, b.w)));
  #pragma unroll
  for (int k = 32; k >= 1; k >>= 1) mx = fmaxf(mx, __shfl_xor(mx, k));
  float se = expf(a.x - mx) + expf(a.y - mx) + expf(a.z - mx) + expf(a.w - mx)
           + expf(b.x - mx) + expf(b.y - mx) + expf(b.z - mx) + expf(b.w - mx);
  #pragma unroll
  for (int k = 32; k >= 1; k >>= 1) se += __shfl_xor(se, k);
  if (lane == 0) {
    const float zlab = Z[(size_t)rloc * CC + labels[row]];
    lossB[row] = mx + logf(se) - zlab;
  }
}

// ---------------- K4: final scalar reduce ----------------
__global__ void k_final(const float* __restrict__ rowsum, const float* __restrict__ pos_e,
                        const float* __restrict__ diag_e, const float* __restrict__ lossB,
                        float* __restrict__ out) {
  __shared__ float redA[4], redB[4];
  const int tid = threadIdx.x;
  float sa = 0.f, sb = 0.f;
  for (int i = tid; i < NN; i += 256) {
    sa += logf(rowsum[i] - diag_e[i]) - logf(pos_e[i]);
    sb += lossB[i];
  }
  const int lane = tid & 63, wv = tid >> 6;
  #pragma unroll
  for (int k = 32; k >= 1; k >>= 1) { sa += __shfl_xor(sa, k); sb += __shfl_xor(sb, k); }
  if (lane == 0) { redA[wv] = sa; redB[wv] = sb; }
  __syncthreads();
  if (tid == 0) {
    const float la = redA[0] + redA[1] + redA[2] + redA[3];
    const float lb = redB[0] + redB[1] + redB[2] + redB[3];
    out[0] = la / (float)NN + lb / (float)NN;
  }
}

extern "C" void kernel_launch(void* const* d_in, const int* in_sizes, int n_in,
                              void* d_out, int out_size, void* d_ws, size_t ws_size,
                              hipStream_t stream) {
  (void)in_sizes; (void)n_in; (void)out_size; (void)ws_size;
  const float* si  = (const float*)d_in[0];
  const float* sj  = (const float*)d_in[1];
  const float* ci  = (const float*)d_in[2];
  const float* cj  = (const float*)d_in[3];
  const float* pi  = (const float*)d_in[4];
  const float* pj  = (const float*)d_in[5];
  const int*   lab = (const int*)d_in[6];
  const float* cst = (const float*)d_in[7];
  const float* cca = (const float*)d_in[8];
  const float* cpl = (const float*)d_in[9];
  const float* cnc = (const float*)d_in[10];

  // ws layout (~7.45 MB of the >=9.47 MB proven budget):
  float* ws     = (float*)d_ws;
  float* Z      = ws;                          // 2048*512 f32 = 4 MB (reused per half)
  float* rowsum = Z + (size_t)BB * CC;         // 4096
  float* pos_e  = rowsum + NN;                 // 4096
  float* diag_e = pos_e + NN;                  // 4096
  float* lossB  = diag_e + NN;                 // 4096
  __hip_bfloat16* fbf = (__hip_bfloat16*)(lossB + NN);          // 3*4096*128 bf16 = 3 MB
  __hip_bfloat16* cbf = fbf + (size_t)3 * NN * DD;              // 3*512*128 bf16 = 384 KB

  hipMemsetAsync(rowsum, 0, NN * sizeof(float), stream);

  k_norm<<<dim3(NN, 3), 64, 0, stream>>>(si, sj, ci, cj, pi, pj, fbf);
  k_prep<<<dim3(CC, 3), 64, 0, stream>>>(cst, cca, cpl, cnc, cbf);
  k_sim<<<528, 256, 0, stream>>>(fbf, rowsum, pos_e, diag_e);   // 32*33/2 triangle tiles
  // proto loss in two half-batches, reusing Z
  k_pmm<<<dim3(CC / 64, BB / 64), 256, 0, stream>>>(fbf, cbf, Z, 0);
  k_smax<<<BB / 4, 256, 0, stream>>>(Z, lab, lossB, 0);
  k_pmm<<<dim3(CC / 64, BB / 64), 256, 0, stream>>>(fbf, cbf, Z, BB);
  k_smax<<<BB / 4, 256, 0, stream>>>(Z, lab, lossB, BB);
  k_final<<<1, 256, 0, stream>>>(rowsum, pos_e, diag_e, lossB, (float*)d_out);
}

// Round 7
// 127.905 us; speedup vs baseline: 7.9122x; 1.0496x over previous
//
#include <hip/hip_runtime.h>
#include <hip/hip_bf16.h>
#include <math.h>

#define BB 2048   // batch per view
#define NN 4096   // 2*BB
#define DD 128    // feature dim per modality
#define CC 512    // classes

typedef __attribute__((ext_vector_type(8))) short bf16x8;   // 8 bf16 = 4 VGPRs
typedef __attribute__((ext_vector_type(4))) float f32x4;

// ---------------- K1: fused l2-normalize(feats) + scale(centroids), bf16 out ----------
// grid.x = NN/4 + CC/4 blocks of 256 (one row per wave); grid.y = modality
__global__ __launch_bounds__(256) void k_normprep(
    const float* __restrict__ si, const float* __restrict__ sj,
    const float* __restrict__ ci, const float* __restrict__ cj,
    const float* __restrict__ pi, const float* __restrict__ pj,
    const float* __restrict__ cst, const float* __restrict__ cca,
    const float* __restrict__ cpl, const float* __restrict__ conc,
    __hip_bfloat16* __restrict__ fbf, __hip_bfloat16* __restrict__ cbf) {
  const int m   = blockIdx.y;
  const int tid = threadIdx.x;
  const int w   = tid >> 6;
  const int t   = tid & 63;
  const float sqw = (m == 0) ? 0.632455532033676f : 0.547722557505166f;  // sqrt(w_m)
  if (blockIdx.x < NN / 4) {
    const int row = blockIdx.x * 4 + w;
    const float* src;
    if (m == 0)      src = (row < BB) ? si : sj;
    else if (m == 1) src = (row < BB) ? ci : cj;
    else             src = (row < BB) ? pi : pj;
    const int r = (row < BB) ? row : row - BB;
    float2 v = ((const float2*)(src + (size_t)r * DD))[t];
    float ss = v.x * v.x + v.y * v.y;
    #pragma unroll
    for (int k = 32; k >= 1; k >>= 1) ss += __shfl_xor(ss, k);
    const float inv = sqw / fmaxf(sqrtf(ss), 1e-12f);
    __hip_bfloat16* db = fbf + (size_t)m * NN * DD + (size_t)row * DD;
    db[2 * t]     = __float2bfloat16(v.x * inv);
    db[2 * t + 1] = __float2bfloat16(v.y * inv);
  } else {
    const int crow = (blockIdx.x - NN / 4) * 4 + w;   // 0..511
    const float* src = (m == 0) ? cst : (m == 1) ? cca : cpl;
    const float sc = sqw / (conc[m * CC + crow] + 1e-12f);
    float2 v = ((const float2*)(src + (size_t)crow * DD))[t];
    __hip_bfloat16* db = cbf + (size_t)m * CC * DD + (size_t)crow * DD;
    db[2 * t]     = __float2bfloat16(v.x * sc);
    db[2 * t + 1] = __float2bfloat16(v.y * sc);
  }
}

// ---------------- K2: symmetric K=384 Gram, LDS-staged, fused exp/row+col reduce -------
// Grid: 528 upper-triangle 128x128 tiles. Block 256 thr = 4 waves (2x2), wave 64x64.
__global__ __launch_bounds__(256, 3) void k_sim(const __hip_bfloat16* __restrict__ fbf,
                                                float* __restrict__ rowsum,
                                                float* __restrict__ pos_e,
                                                float* __restrict__ diag_e) {
  __shared__ bf16x8 As[1024];   // 16 KB
  __shared__ bf16x8 Bs[1024];   // 16 KB

  int tB = blockIdx.x;
  int by = 0;
  while (tB >= 32 - by) { tB -= 32 - by; ++by; }
  const int bx = by + tB;
  const bool diag = (by == bx);
  const int rowBase = by * 128;
  const int colBase = bx * 128;

  const int tid  = threadIdx.x;
  const int lane = tid & 63;
  const int wid  = tid >> 6;
  const int wr   = wid >> 1, wc = wid & 1;
  const int l15  = lane & 15;
  const int kg   = lane >> 4;

  const int srow = tid >> 3;           // 0..31
  const int kc   = tid & 7;
  const int sc   = kc ^ (srow & 7);    // swizzled chunk

  f32x4 acc[4][4] = {};
  bf16x8 ra[4], rb[4];

  {
    const __hip_bfloat16* F = fbf;
    #pragma unroll
    for (int q = 0; q < 4; ++q) {
      ra[q] = *(const bf16x8*)(F + (size_t)(rowBase + q * 32 + srow) * DD + kc * 8);
      if (!diag)
        rb[q] = *(const bf16x8*)(F + (size_t)(colBase + q * 32 + srow) * DD + kc * 8);
    }
  }

  for (int t = 0; t < 6; ++t) {        // K = 384 = 6 x BK64
    #pragma unroll
    for (int q = 0; q < 4; ++q) {
      As[(q * 32 + srow) * 8 + sc] = ra[q];
      if (!diag) Bs[(q * 32 + srow) * 8 + sc] = rb[q];
    }
    __syncthreads();

    if (t < 5) {
      const __hip_bfloat16* F = fbf + (size_t)((t + 1) >> 1) * NN * DD + ((t + 1) & 1) * 64;
      #pragma unroll
      for (int q = 0; q < 4; ++q) {
        ra[q] = *(const bf16x8*)(F + (size_t)(rowBase + q * 32 + srow) * DD + kc * 8);
        if (!diag)
          rb[q] = *(const bf16x8*)(F + (size_t)(colBase + q * 32 + srow) * DD + kc * 8);
      }
    }

    const bf16x8* Bsrc = diag ? As : Bs;
    #pragma unroll
    for (int ks2 = 0; ks2 < 2; ++ks2) {
      bf16x8 a[4], b[4];
      const int ch = (ks2 * 4 + kg) ^ (l15 & 7);
      #pragma unroll
      for (int ti = 0; ti < 4; ++ti)
        a[ti] = As[(wr * 64 + ti * 16 + l15) * 8 + ch];
      #pragma unroll
      for (int tj = 0; tj < 4; ++tj)
        b[tj] = Bsrc[(wc * 64 + tj * 16 + l15) * 8 + ch];
      #pragma unroll
      for (int ti = 0; ti < 4; ++ti)
        #pragma unroll
        for (int tj = 0; tj < 4; ++tj)
          acc[ti][tj] = __builtin_amdgcn_mfma_f32_16x16x32_bf16(a[ti], b[tj], acc[ti][tj], 0, 0, 0);
    }
    __syncthreads();
  }

  float csum[4] = {0.f, 0.f, 0.f, 0.f};
  #pragma unroll
  for (int ti = 0; ti < 4; ++ti) {
    #pragma unroll
    for (int j = 0; j < 4; ++j) {
      const int i = rowBase + wr * 64 + ti * 16 + kg * 4 + j;
      float rsum = 0.f;
      #pragma unroll
      for (int tj = 0; tj < 4; ++tj) {
        const int jcol = colBase + wc * 64 + tj * 16 + l15;
        const float e = expf(2.0f * acc[ti][tj][j]);
        rsum += e;
        csum[tj] += e;
        if (diag) {
          if (jcol == i) diag_e[i] = e;
        } else if (jcol == ((i + BB) & (NN - 1))) {
          pos_e[i] = e;
          pos_e[jcol] = e;
        }
      }
      #pragma unroll
      for (int msk = 8; msk >= 1; msk >>= 1) rsum += __shfl_xor(rsum, msk);
      if (l15 == 0) atomicAdd(&rowsum[i], rsum);
    }
  }
  if (!diag) {
    #pragma unroll
    for (int tj = 0; tj < 4; ++tj) {
      float v = csum[tj];
      v += __shfl_xor(v, 16);
      v += __shfl_xor(v, 32);
      if (lane < 16) atomicAdd(&rowsum[colBase + wc * 64 + tj * 16 + l15], v);
    }
  }
}

// ---------------- K3: fully-fused proto loss: GEMM + in-block log-softmax CE ----------
// Grid: 256 blocks x 256 thr. Block = 16 rows x 512 classes; wave w owns classes
// [w*128, (w+1)*128) via 8 16x16 frags. acc map: row=kg*4+j, col=w*128+tj*16+l15.
__global__ __launch_bounds__(256) void k_proto2(const __hip_bfloat16* __restrict__ fbf,
                                                const __hip_bfloat16* __restrict__ cbf,
                                                const int* __restrict__ labels,
                                                float* __restrict__ lossB) {
  __shared__ int   slab[16];
  __shared__ float wmax[4][16], wsum[4][16], zlab[16];
  const int tid  = threadIdx.x;
  const int lane = tid & 63;
  const int w    = tid >> 6;
  const int l15  = lane & 15;
  const int kg   = lane >> 4;
  const int row0 = blockIdx.x * 16;

  if (tid < 16) slab[tid] = labels[row0 + tid];
  __syncthreads();

  f32x4 acc[8] = {};
  #pragma unroll
  for (int ks = 0; ks < 12; ++ks) {
    const int koff = (ks & 3) * 32 + kg * 8;
    const __hip_bfloat16* F  = fbf + (size_t)(ks >> 2) * NN * DD + koff;
    const __hip_bfloat16* Cm = cbf + (size_t)(ks >> 2) * CC * DD + koff;
    const bf16x8 af = *(const bf16x8*)(F + (size_t)(row0 + l15) * DD);
    bf16x8 bf_[8];
    #pragma unroll
    for (int tj = 0; tj < 8; ++tj)
      bf_[tj] = *(const bf16x8*)(Cm + (size_t)(w * 128 + tj * 16 + l15) * DD);
    #pragma unroll
    for (int tj = 0; tj < 8; ++tj)
      acc[tj] = __builtin_amdgcn_mfma_f32_16x16x32_bf16(af, bf_[tj], acc[tj], 0, 0, 0);
  }

  // label logit capture (exactly one lane block-wide matches each row)
  #pragma unroll
  for (int j = 0; j < 4; ++j) {
    const int r = kg * 4 + j;
    #pragma unroll
    for (int tj = 0; tj < 8; ++tj) {
      const int c = w * 128 + tj * 16 + l15;
      if (c == slab[r]) zlab[r] = acc[tj][j];
    }
  }

  // per-wave per-row max over its 128-class slice
  #pragma unroll
  for (int j = 0; j < 4; ++j) {
    float mx = acc[0][j];
    #pragma unroll
    for (int tj = 1; tj < 8; ++tj) mx = fmaxf(mx, acc[tj][j]);
    #pragma unroll
    for (int msk = 8; msk >= 1; msk >>= 1) mx = fmaxf(mx, __shfl_xor(mx, msk));
    if (l15 == 0) wmax[w][kg * 4 + j] = mx;
  }
  __syncthreads();

  #pragma unroll
  for (int j = 0; j < 4; ++j) {
    const int r = kg * 4 + j;
    const float bmx = fmaxf(fmaxf(wmax[0][r], wmax[1][r]), fmaxf(wmax[2][r], wmax[3][r]));
    float se = 0.f;
    #pragma unroll
    for (int tj = 0; tj < 8; ++tj) se += expf(acc[tj][j] - bmx);
    #pragma unroll
    for (int msk = 8; msk >= 1; msk >>= 1) se += __shfl_xor(se, msk);
    if (l15 == 0) wsum[w][r] = se;
  }
  __syncthreads();

  if (tid < 16) {
    const int r = tid;
    const float bmx = fmaxf(fmaxf(wmax[0][r], wmax[1][r]), fmaxf(wmax[2][r], wmax[3][r]));
    const float s = wsum[0][r] + wsum[1][r] + wsum[2][r] + wsum[3][r];
    lossB[row0 + r] = bmx + logf(s) - zlab[r];
  }
}

// ---------------- K4: final scalar reduce ----------------
__global__ void k_final(const float* __restrict__ rowsum, const float* __restrict__ pos_e,
                        const float* __restrict__ diag_e, const float* __restrict__ lossB,
                        float* __restrict__ out) {
  __shared__ float redA[4], redB[4];
  const int tid = threadIdx.x;
  float sa = 0.f, sb = 0.f;
  for (int i = tid; i < NN; i += 256) {
    sa += logf(rowsum[i] - diag_e[i]) - logf(pos_e[i]);
    sb += lossB[i];
  }
  const int lane = tid & 63, wv = tid >> 6;
  #pragma unroll
  for (int k = 32; k >= 1; k >>= 1) { sa += __shfl_xor(sa, k); sb += __shfl_xor(sb, k); }
  if (lane == 0) { redA[wv] = sa; redB[wv] = sb; }
  __syncthreads();
  if (tid == 0) {
    const float la = redA[0] + redA[1] + redA[2] + redA[3];
    const float lb = redB[0] + redB[1] + redB[2] + redB[3];
    out[0] = la / (float)NN + lb / (float)NN;
  }
}

extern "C" void kernel_launch(void* const* d_in, const int* in_sizes, int n_in,
                              void* d_out, int out_size, void* d_ws, size_t ws_size,
                              hipStream_t stream) {
  (void)in_sizes; (void)n_in; (void)out_size; (void)ws_size;
  const float* si  = (const float*)d_in[0];
  const float* sj  = (const float*)d_in[1];
  const float* ci  = (const float*)d_in[2];
  const float* cj  = (const float*)d_in[3];
  const float* pi  = (const float*)d_in[4];
  const float* pj  = (const float*)d_in[5];
  const int*   lab = (const int*)d_in[6];
  const float* cst = (const float*)d_in[7];
  const float* cca = (const float*)d_in[8];
  const float* cpl = (const float*)d_in[9];
  const float* cnc = (const float*)d_in[10];

  // ws layout (~3.5 MB): small f32 arrays + bf16 feats/centroids
  float* ws     = (float*)d_ws;
  float* rowsum = ws;                          // 4096
  float* pos_e  = rowsum + NN;                 // 4096
  float* diag_e = pos_e + NN;                  // 4096
  float* lossB  = diag_e + NN;                 // 4096
  __hip_bfloat16* fbf = (__hip_bfloat16*)(lossB + NN);          // 3*4096*128 bf16 = 3 MB
  __hip_bfloat16* cbf = fbf + (size_t)3 * NN * DD;              // 3*512*128 bf16 = 384 KB

  hipMemsetAsync(rowsum, 0, NN * sizeof(float), stream);

  k_normprep<<<dim3(NN / 4 + CC / 4, 3), 256, 0, stream>>>(si, sj, ci, cj, pi, pj,
                                                           cst, cca, cpl, cnc, fbf, cbf);
  k_sim<<<528, 256, 0, stream>>>(fbf, rowsum, pos_e, diag_e);   // 32*33/2 triangle tiles
  k_proto2<<<NN / 16, 256, 0, stream>>>(fbf, cbf, lab, lossB);
  k_final<<<1, 256, 0, stream>>>(rowsum, pos_e, diag_e, lossB, (float*)d_out);
}

// Round 8
// 126.914 us; speedup vs baseline: 7.9740x; 1.0078x over previous
//
#include <hip/hip_runtime.h>
#include <hip/hip_bf16.h>
#include <math.h>

#define BB 2048   // batch per view
#define NN 4096   // 2*BB
#define DD 128    // feature dim per modality
#define CC 512    // classes
#define NSIM 528  // 32*33/2 upper-triangle 128x128 tiles

typedef __attribute__((ext_vector_type(8))) short bf16x8;   // 8 bf16 = 4 VGPRs
typedef __attribute__((ext_vector_type(4))) float f32x4;

// ---------------- K1: fused l2-normalize(feats) + scale(centroids), bf16 out ----------
__global__ __launch_bounds__(256) void k_normprep(
    const float* __restrict__ si, const float* __restrict__ sj,
    const float* __restrict__ ci, const float* __restrict__ cj,
    const float* __restrict__ pi, const float* __restrict__ pj,
    const float* __restrict__ cst, const float* __restrict__ cca,
    const float* __restrict__ cpl, const float* __restrict__ conc,
    __hip_bfloat16* __restrict__ fbf, __hip_bfloat16* __restrict__ cbf) {
  const int m   = blockIdx.y;
  const int tid = threadIdx.x;
  const int w   = tid >> 6;
  const int t   = tid & 63;
  const float sqw = (m == 0) ? 0.632455532033676f : 0.547722557505166f;  // sqrt(w_m)
  if (blockIdx.x < NN / 4) {
    const int row = blockIdx.x * 4 + w;
    const float* src;
    if (m == 0)      src = (row < BB) ? si : sj;
    else if (m == 1) src = (row < BB) ? ci : cj;
    else             src = (row < BB) ? pi : pj;
    const int r = (row < BB) ? row : row - BB;
    float2 v = ((const float2*)(src + (size_t)r * DD))[t];
    float ss = v.x * v.x + v.y * v.y;
    #pragma unroll
    for (int k = 32; k >= 1; k >>= 1) ss += __shfl_xor(ss, k);
    const float inv = sqw / fmaxf(sqrtf(ss), 1e-12f);
    __hip_bfloat16* db = fbf + (size_t)m * NN * DD + (size_t)row * DD;
    db[2 * t]     = __float2bfloat16(v.x * inv);
    db[2 * t + 1] = __float2bfloat16(v.y * inv);
  } else {
    const int crow = (blockIdx.x - NN / 4) * 4 + w;   // 0..511
    const float* src = (m == 0) ? cst : (m == 1) ? cca : cpl;
    const float sc = sqw / (conc[m * CC + crow] + 1e-12f);
    float2 v = ((const float2*)(src + (size_t)crow * DD))[t];
    __hip_bfloat16* db = cbf + (size_t)m * CC * DD + (size_t)crow * DD;
    db[2 * t]     = __float2bfloat16(v.x * sc);
    db[2 * t + 1] = __float2bfloat16(v.y * sc);
  }
}

// ---------------- K2: merged sim-Gram + proto-logits kernel ----------------
// blocks [0, 528): symmetric K=384 Gram tile (128x128), LDS-staged (round-6 proven path)
// blocks [528, 1040): proto partial — 16 rows x 256 classes, partial lse to pmax/psum/zl
__global__ __launch_bounds__(256, 3) void k_main(const __hip_bfloat16* __restrict__ fbf,
                                                 const __hip_bfloat16* __restrict__ cbf,
                                                 const int* __restrict__ labels,
                                                 float* __restrict__ rowsum,
                                                 float* __restrict__ pos_e,
                                                 float* __restrict__ diag_e,
                                                 float* __restrict__ pmax_g,
                                                 float* __restrict__ psum_g,
                                                 float* __restrict__ zl_g) {
  __shared__ bf16x8 As[1024];   // 16 KB
  __shared__ bf16x8 Bs[1024];   // 16 KB

  const int tid  = threadIdx.x;
  const int lane = tid & 63;
  const int wid  = tid >> 6;
  const int l15  = lane & 15;
  const int kg   = lane >> 4;

  if (blockIdx.x < NSIM) {
    // ================= SIM path (identical to round-6 k_sim) =================
    int tB = blockIdx.x;
    int by = 0;
    while (tB >= 32 - by) { tB -= 32 - by; ++by; }
    const int bx = by + tB;
    const bool diag = (by == bx);
    const int rowBase = by * 128;
    const int colBase = bx * 128;

    const int wr = wid >> 1, wc = wid & 1;
    const int srow = tid >> 3;           // 0..31
    const int kc   = tid & 7;
    const int sc   = kc ^ (srow & 7);    // swizzled chunk

    f32x4 acc[4][4] = {};
    bf16x8 ra[4], rb[4];

    {
      const __hip_bfloat16* F = fbf;
      #pragma unroll
      for (int q = 0; q < 4; ++q) {
        ra[q] = *(const bf16x8*)(F + (size_t)(rowBase + q * 32 + srow) * DD + kc * 8);
        if (!diag)
          rb[q] = *(const bf16x8*)(F + (size_t)(colBase + q * 32 + srow) * DD + kc * 8);
      }
    }

    for (int t = 0; t < 6; ++t) {        // K = 384 = 6 x BK64
      #pragma unroll
      for (int q = 0; q < 4; ++q) {
        As[(q * 32 + srow) * 8 + sc] = ra[q];
        if (!diag) Bs[(q * 32 + srow) * 8 + sc] = rb[q];
      }
      __syncthreads();

      if (t < 5) {
        const __hip_bfloat16* F = fbf + (size_t)((t + 1) >> 1) * NN * DD + ((t + 1) & 1) * 64;
        #pragma unroll
        for (int q = 0; q < 4; ++q) {
          ra[q] = *(const bf16x8*)(F + (size_t)(rowBase + q * 32 + srow) * DD + kc * 8);
          if (!diag)
            rb[q] = *(const bf16x8*)(F + (size_t)(colBase + q * 32 + srow) * DD + kc * 8);
        }
      }

      const bf16x8* Bsrc = diag ? As : Bs;
      #pragma unroll
      for (int ks2 = 0; ks2 < 2; ++ks2) {
        bf16x8 a[4], b[4];
        const int ch = (ks2 * 4 + kg) ^ (l15 & 7);
        #pragma unroll
        for (int ti = 0; ti < 4; ++ti)
          a[ti] = As[(wr * 64 + ti * 16 + l15) * 8 + ch];
        #pragma unroll
        for (int tj = 0; tj < 4; ++tj)
          b[tj] = Bsrc[(wc * 64 + tj * 16 + l15) * 8 + ch];
        #pragma unroll
        for (int ti = 0; ti < 4; ++ti)
          #pragma unroll
          for (int tj = 0; tj < 4; ++tj)
            acc[ti][tj] = __builtin_amdgcn_mfma_f32_16x16x32_bf16(a[ti], b[tj], acc[ti][tj], 0, 0, 0);
      }
      __syncthreads();
    }

    float csum[4] = {0.f, 0.f, 0.f, 0.f};
    #pragma unroll
    for (int ti = 0; ti < 4; ++ti) {
      #pragma unroll
      for (int j = 0; j < 4; ++j) {
        const int i = rowBase + wr * 64 + ti * 16 + kg * 4 + j;
        float rsum = 0.f;
        #pragma unroll
        for (int tj = 0; tj < 4; ++tj) {
          const int jcol = colBase + wc * 64 + tj * 16 + l15;
          const float e = expf(2.0f * acc[ti][tj][j]);
          rsum += e;
          csum[tj] += e;
          if (diag) {
            if (jcol == i) diag_e[i] = e;
          } else if (jcol == ((i + BB) & (NN - 1))) {
            pos_e[i] = e;
            pos_e[jcol] = e;
          }
        }
        #pragma unroll
        for (int msk = 8; msk >= 1; msk >>= 1) rsum += __shfl_xor(rsum, msk);
        if (l15 == 0) atomicAdd(&rowsum[i], rsum);
      }
    }
    if (!diag) {
      #pragma unroll
      for (int tj = 0; tj < 4; ++tj) {
        float v = csum[tj];
        v += __shfl_xor(v, 16);
        v += __shfl_xor(v, 32);
        if (lane < 16) atomicAdd(&rowsum[colBase + wc * 64 + tj * 16 + l15], v);
      }
    }
  } else {
    // ================= PROTO path: 16 rows x 256 classes, partial lse =================
    float* wmaxs = (float*)As;            // [4][16]
    float* wsums = wmaxs + 64;            // [4][16]
    int*   slab  = (int*)(wsums + 64);    // [16]

    const int bidp = blockIdx.x - NSIM;   // 0..511
    const int half = bidp & 1;
    const int row0 = (bidp >> 1) * 16;
    const int cbase = half * 256 + wid * 64;

    if (tid < 16) slab[tid] = labels[row0 + tid];
    __syncthreads();

    f32x4 acc[4] = {};
    #pragma unroll
    for (int ks = 0; ks < 12; ++ks) {
      const int koff = (ks & 3) * 32 + kg * 8;
      const __hip_bfloat16* F  = fbf + (size_t)(ks >> 2) * NN * DD + koff;
      const __hip_bfloat16* Cm = cbf + (size_t)(ks >> 2) * CC * DD + koff;
      const bf16x8 af = *(const bf16x8*)(F + (size_t)(row0 + l15) * DD);
      bf16x8 bf_[4];
      #pragma unroll
      for (int tj = 0; tj < 4; ++tj)
        bf_[tj] = *(const bf16x8*)(Cm + (size_t)(cbase + tj * 16 + l15) * DD);
      #pragma unroll
      for (int tj = 0; tj < 4; ++tj)
        acc[tj] = __builtin_amdgcn_mfma_f32_16x16x32_bf16(af, bf_[tj], acc[tj], 0, 0, 0);
    }

    // label logit capture (at most one lane block-wide matches each row)
    #pragma unroll
    for (int j = 0; j < 4; ++j) {
      const int r = kg * 4 + j;
      #pragma unroll
      for (int tj = 0; tj < 4; ++tj) {
        const int c = cbase + tj * 16 + l15;
        if (c == slab[r]) zl_g[row0 + r] = acc[tj][j];
      }
    }

    // per-wave per-row max over its 64-class slice
    #pragma unroll
    for (int j = 0; j < 4; ++j) {
      float mx = acc[0][j];
      #pragma unroll
      for (int tj = 1; tj < 4; ++tj) mx = fmaxf(mx, acc[tj][j]);
      #pragma unroll
      for (int msk = 8; msk >= 1; msk >>= 1) mx = fmaxf(mx, __shfl_xor(mx, msk));
      if (l15 == 0) wmaxs[wid * 16 + kg * 4 + j] = mx;
    }
    __syncthreads();

    #pragma unroll
    for (int j = 0; j < 4; ++j) {
      const int r = kg * 4 + j;
      const float bmx = fmaxf(fmaxf(wmaxs[0 * 16 + r], wmaxs[1 * 16 + r]),
                              fmaxf(wmaxs[2 * 16 + r], wmaxs[3 * 16 + r]));
      float se = 0.f;
      #pragma unroll
      for (int tj = 0; tj < 4; ++tj) se += expf(acc[tj][j] - bmx);
      #pragma unroll
      for (int msk = 8; msk >= 1; msk >>= 1) se += __shfl_xor(se, msk);
      if (l15 == 0) wsums[wid * 16 + r] = se;
    }
    __syncthreads();

    if (tid < 16) {
      const int r = tid;
      const float bmx = fmaxf(fmaxf(wmaxs[0 * 16 + r], wmaxs[1 * 16 + r]),
                              fmaxf(wmaxs[2 * 16 + r], wmaxs[3 * 16 + r]));
      const float s = wsums[0 * 16 + r] + wsums[1 * 16 + r] +
                      wsums[2 * 16 + r] + wsums[3 * 16 + r];
      pmax_g[(size_t)half * NN + row0 + r] = bmx;
      psum_g[(size_t)half * NN + row0 + r] = s;
    }
  }
}

// ---------------- K4: final scalar reduce (combines proto halves exactly) -------------
__global__ void k_final(const float* __restrict__ rowsum, const float* __restrict__ pos_e,
                        const float* __restrict__ diag_e, const float* __restrict__ pmax_g,
                        const float* __restrict__ psum_g, const float* __restrict__ zl_g,
                        float* __restrict__ out) {
  __shared__ float redA[4], redB[4];
  const int tid = threadIdx.x;
  float sa = 0.f, sb = 0.f;
  for (int i = tid; i < NN; i += 256) {
    sa += logf(rowsum[i] - diag_e[i]) - logf(pos_e[i]);
    const float m0 = pmax_g[i], m1 = pmax_g[NN + i];
    const float M = fmaxf(m0, m1);
    const float s = psum_g[i] * expf(m0 - M) + psum_g[NN + i] * expf(m1 - M);
    sb += M + logf(s) - zl_g[i];
  }
  const int lane = tid & 63, wv = tid >> 6;
  #pragma unroll
  for (int k = 32; k >= 1; k >>= 1) { sa += __shfl_xor(sa, k); sb += __shfl_xor(sb, k); }
  if (lane == 0) { redA[wv] = sa; redB[wv] = sb; }
  __syncthreads();
  if (tid == 0) {
    const float la = redA[0] + redA[1] + redA[2] + redA[3];
    const float lb = redB[0] + redB[1] + redB[2] + redB[3];
    out[0] = la / (float)NN + lb / (float)NN;
  }
}

extern "C" void kernel_launch(void* const* d_in, const int* in_sizes, int n_in,
                              void* d_out, int out_size, void* d_ws, size_t ws_size,
                              hipStream_t stream) {
  (void)in_sizes; (void)n_in; (void)out_size; (void)ws_size;
  const float* si  = (const float*)d_in[0];
  const float* sj  = (const float*)d_in[1];
  const float* ci  = (const float*)d_in[2];
  const float* cj  = (const float*)d_in[3];
  const float* pi  = (const float*)d_in[4];
  const float* pj  = (const float*)d_in[5];
  const int*   lab = (const int*)d_in[6];
  const float* cst = (const float*)d_in[7];
  const float* cca = (const float*)d_in[8];
  const float* cpl = (const float*)d_in[9];
  const float* cnc = (const float*)d_in[10];

  // ws layout (~3.6 MB): small f32 arrays + bf16 feats/centroids
  float* ws     = (float*)d_ws;
  float* rowsum = ws;                          // 4096
  float* pos_e  = rowsum + NN;                 // 4096
  float* diag_e = pos_e + NN;                  // 4096
  float* pmax_g = diag_e + NN;                 // 2*4096
  float* psum_g = pmax_g + 2 * NN;             // 2*4096
  float* zl_g   = psum_g + 2 * NN;             // 4096
  __hip_bfloat16* fbf = (__hip_bfloat16*)(zl_g + NN);           // 3*4096*128 bf16 = 3 MB
  __hip_bfloat16* cbf = fbf + (size_t)3 * NN * DD;              // 3*512*128 bf16 = 384 KB

  hipMemsetAsync(rowsum, 0, NN * sizeof(float), stream);

  k_normprep<<<dim3(NN / 4 + CC / 4, 3), 256, 0, stream>>>(si, sj, ci, cj, pi, pj,
                                                           cst, cca, cpl, cnc, fbf, cbf);
  k_main<<<NSIM + 2 * (NN / 16), 256, 0, stream>>>(fbf, cbf, lab, rowsum, pos_e, diag_e,
                                                   pmax_g, psum_g, zl_g);
  k_final<<<1, 256, 0, stream>>>(rowsum, pos_e, diag_e, pmax_g, psum_g, zl_g, (float*)d_out);
}

// Round 9
// 118.152 us; speedup vs baseline: 8.5653x; 1.0742x over previous
//
#include <hip/hip_runtime.h>
#include <hip/hip_bf16.h>
#include <math.h>

#define BB 2048   // batch per view
#define NN 4096   // 2*BB
#define DD 128    // feature dim per modality
#define CC 512    // classes
#define NSIM 528  // 32*33/2 upper-triangle 128x128 tiles
#define NPROTO 128// (4096/64 row-groups) x 2 class-halves

typedef __attribute__((ext_vector_type(8))) short bf16x8;   // 8 bf16 = 4 VGPRs
typedef __attribute__((ext_vector_type(4))) float f32x4;

// ---------------- K1: fused l2-normalize(feats) + scale(centroids) + rowsum zero -------
// 512-thr blocks, 1 row per wave. grid.x = NN/8 + CC/8 = 576, grid.y = modality.
__global__ __launch_bounds__(512) void k_normprep(
    const float* __restrict__ si, const float* __restrict__ sj,
    const float* __restrict__ ci, const float* __restrict__ cj,
    const float* __restrict__ pi, const float* __restrict__ pj,
    const float* __restrict__ cst, const float* __restrict__ cca,
    const float* __restrict__ cpl, const float* __restrict__ conc,
    __hip_bfloat16* __restrict__ fbf, __hip_bfloat16* __restrict__ cbf,
    float* __restrict__ rowsum) {
  const int m   = blockIdx.y;
  const int tid = threadIdx.x;
  const int w   = tid >> 6;
  const int t   = tid & 63;
  const float sqw = (m == 0) ? 0.632455532033676f : 0.547722557505166f;  // sqrt(w_m)

  // fold the rowsum zeroing into this dispatch (replaces a memset node)
  if (m == 2 && blockIdx.x < 2) {
    const int i = (blockIdx.x * 512 + tid) * 4;
    *(float4*)(rowsum + i) = make_float4(0.f, 0.f, 0.f, 0.f);
  }

  if (blockIdx.x < NN / 8) {
    const int row = blockIdx.x * 8 + w;
    const float* src;
    if (m == 0)      src = (row < BB) ? si : sj;
    else if (m == 1) src = (row < BB) ? ci : cj;
    else             src = (row < BB) ? pi : pj;
    const int r = (row < BB) ? row : row - BB;
    float2 v = ((const float2*)(src + (size_t)r * DD))[t];
    float ss = v.x * v.x + v.y * v.y;
    #pragma unroll
    for (int k = 32; k >= 1; k >>= 1) ss += __shfl_xor(ss, k);
    const float inv = sqw / fmaxf(sqrtf(ss), 1e-12f);
    __hip_bfloat16* db = fbf + (size_t)m * NN * DD + (size_t)row * DD;
    db[2 * t]     = __float2bfloat16(v.x * inv);
    db[2 * t + 1] = __float2bfloat16(v.y * inv);
  } else {
    const int crow = (blockIdx.x - NN / 8) * 8 + w;   // 0..511
    const float* src = (m == 0) ? cst : (m == 1) ? cca : cpl;
    const float sc = sqw / (conc[m * CC + crow] + 1e-12f);
    float2 v = ((const float2*)(src + (size_t)crow * DD))[t];
    __hip_bfloat16* db = cbf + (size_t)m * CC * DD + (size_t)crow * DD;
    db[2 * t]     = __float2bfloat16(v.x * sc);
    db[2 * t + 1] = __float2bfloat16(v.y * sc);
  }
}

// ---------------- K2: merged sim-Gram + proto-logits kernel ----------------
// blocks [0, 528): symmetric K=384 Gram tile (128x128), LDS-staged (round-6 proven path)
// blocks [528, 656): proto partial — 64 rows x 256 classes, partial lse
__global__ __launch_bounds__(256, 3) void k_main(const __hip_bfloat16* __restrict__ fbf,
                                                 const __hip_bfloat16* __restrict__ cbf,
                                                 const int* __restrict__ labels,
                                                 float* __restrict__ rowsum,
                                                 float* __restrict__ pos_e,
                                                 float* __restrict__ diag_e,
                                                 float* __restrict__ pmax_g,
                                                 float* __restrict__ psum_g,
                                                 float* __restrict__ zl_g) {
  __shared__ bf16x8 As[1024];   // 16 KB
  __shared__ bf16x8 Bs[1024];   // 16 KB

  const int tid  = threadIdx.x;
  const int lane = tid & 63;
  const int wid  = tid >> 6;
  const int l15  = lane & 15;
  const int kg   = lane >> 4;

  if (blockIdx.x < NSIM) {
    // ================= SIM path (identical to round-6 k_sim) =================
    int tB = blockIdx.x;
    int by = 0;
    while (tB >= 32 - by) { tB -= 32 - by; ++by; }
    const int bx = by + tB;
    const bool diag = (by == bx);
    const int rowBase = by * 128;
    const int colBase = bx * 128;

    const int wr = wid >> 1, wc = wid & 1;
    const int srow = tid >> 3;           // 0..31
    const int kc   = tid & 7;
    const int sc   = kc ^ (srow & 7);    // swizzled chunk

    f32x4 acc[4][4] = {};
    bf16x8 ra[4], rb[4];

    {
      const __hip_bfloat16* F = fbf;
      #pragma unroll
      for (int q = 0; q < 4; ++q) {
        ra[q] = *(const bf16x8*)(F + (size_t)(rowBase + q * 32 + srow) * DD + kc * 8);
        if (!diag)
          rb[q] = *(const bf16x8*)(F + (size_t)(colBase + q * 32 + srow) * DD + kc * 8);
      }
    }

    for (int t = 0; t < 6; ++t) {        // K = 384 = 6 x BK64
      #pragma unroll
      for (int q = 0; q < 4; ++q) {
        As[(q * 32 + srow) * 8 + sc] = ra[q];
        if (!diag) Bs[(q * 32 + srow) * 8 + sc] = rb[q];
      }
      __syncthreads();

      if (t < 5) {
        const __hip_bfloat16* F = fbf + (size_t)((t + 1) >> 1) * NN * DD + ((t + 1) & 1) * 64;
        #pragma unroll
        for (int q = 0; q < 4; ++q) {
          ra[q] = *(const bf16x8*)(F + (size_t)(rowBase + q * 32 + srow) * DD + kc * 8);
          if (!diag)
            rb[q] = *(const bf16x8*)(F + (size_t)(colBase + q * 32 + srow) * DD + kc * 8);
        }
      }

      const bf16x8* Bsrc = diag ? As : Bs;
      #pragma unroll
      for (int ks2 = 0; ks2 < 2; ++ks2) {
        bf16x8 a[4], b[4];
        const int ch = (ks2 * 4 + kg) ^ (l15 & 7);
        #pragma unroll
        for (int ti = 0; ti < 4; ++ti)
          a[ti] = As[(wr * 64 + ti * 16 + l15) * 8 + ch];
        #pragma unroll
        for (int tj = 0; tj < 4; ++tj)
          b[tj] = Bsrc[(wc * 64 + tj * 16 + l15) * 8 + ch];
        #pragma unroll
        for (int ti = 0; ti < 4; ++ti)
          #pragma unroll
          for (int tj = 0; tj < 4; ++tj)
            acc[ti][tj] = __builtin_amdgcn_mfma_f32_16x16x32_bf16(a[ti], b[tj], acc[ti][tj], 0, 0, 0);
      }
      __syncthreads();
    }

    float csum[4] = {0.f, 0.f, 0.f, 0.f};
    #pragma unroll
    for (int ti = 0; ti < 4; ++ti) {
      #pragma unroll
      for (int j = 0; j < 4; ++j) {
        const int i = rowBase + wr * 64 + ti * 16 + kg * 4 + j;
        float rsum = 0.f;
        #pragma unroll
        for (int tj = 0; tj < 4; ++tj) {
          const int jcol = colBase + wc * 64 + tj * 16 + l15;
          const float e = expf(2.0f * acc[ti][tj][j]);
          rsum += e;
          csum[tj] += e;
          if (diag) {
            if (jcol == i) diag_e[i] = e;
          } else if (jcol == ((i + BB) & (NN - 1))) {
            pos_e[i] = e;
            pos_e[jcol] = e;
          }
        }
        #pragma unroll
        for (int msk = 8; msk >= 1; msk >>= 1) rsum += __shfl_xor(rsum, msk);
        if (l15 == 0) atomicAdd(&rowsum[i], rsum);
      }
    }
    if (!diag) {
      #pragma unroll
      for (int tj = 0; tj < 4; ++tj) {
        float v = csum[tj];
        v += __shfl_xor(v, 16);
        v += __shfl_xor(v, 32);
        if (lane < 16) atomicAdd(&rowsum[colBase + wc * 64 + tj * 16 + l15], v);
      }
    }
  } else {
    // ========== PROTO path: 64 rows x 256 classes, 16 MFMA : 8 loads per K-step =======
    float* wmaxs = (float*)As;            // [4][64]
    float* wsums = wmaxs + 256;           // [4][64]
    int*   slab  = (int*)(wsums + 256);   // [64]

    const int bidp = blockIdx.x - NSIM;   // 0..127
    const int half = bidp & 1;
    const int row0 = (bidp >> 1) * 64;
    const int cbase = half * 256 + wid * 64;

    if (tid < 64) slab[tid] = labels[row0 + tid];
    __syncthreads();

    f32x4 acc[4][4] = {};                 // [row-frag][col-frag]
    #pragma unroll
    for (int ks = 0; ks < 12; ++ks) {
      const int koff = (ks & 3) * 32 + kg * 8;
      const __hip_bfloat16* F  = fbf + (size_t)(ks >> 2) * NN * DD + koff;
      const __hip_bfloat16* Cm = cbf + (size_t)(ks >> 2) * CC * DD + koff;
      bf16x8 af[4], bfr[4];
      #pragma unroll
      for (int ti = 0; ti < 4; ++ti)
        af[ti] = *(const bf16x8*)(F + (size_t)(row0 + ti * 16 + l15) * DD);
      #pragma unroll
      for (int tj = 0; tj < 4; ++tj)
        bfr[tj] = *(const bf16x8*)(Cm + (size_t)(cbase + tj * 16 + l15) * DD);
      #pragma unroll
      for (int ti = 0; ti < 4; ++ti)
        #pragma unroll
        for (int tj = 0; tj < 4; ++tj)
          acc[ti][tj] = __builtin_amdgcn_mfma_f32_16x16x32_bf16(af[ti], bfr[tj], acc[ti][tj], 0, 0, 0);
    }

    // label logit capture (exactly one lane device-wide matches each row)
    #pragma unroll
    for (int ti = 0; ti < 4; ++ti) {
      #pragma unroll
      for (int j = 0; j < 4; ++j) {
        const int r = ti * 16 + kg * 4 + j;
        #pragma unroll
        for (int tj = 0; tj < 4; ++tj) {
          const int c = cbase + tj * 16 + l15;
          if (c == slab[r]) zl_g[row0 + r] = acc[ti][tj][j];
        }
      }
    }

    // per-wave per-row max over its 64-class slice
    #pragma unroll
    for (int ti = 0; ti < 4; ++ti) {
      #pragma unroll
      for (int j = 0; j < 4; ++j) {
        const int r = ti * 16 + kg * 4 + j;
        float mx = acc[ti][0][j];
        #pragma unroll
        for (int tj = 1; tj < 4; ++tj) mx = fmaxf(mx, acc[ti][tj][j]);
        #pragma unroll
        for (int msk = 8; msk >= 1; msk >>= 1) mx = fmaxf(mx, __shfl_xor(mx, msk));
        if (l15 == 0) wmaxs[wid * 64 + r] = mx;
      }
    }
    __syncthreads();

    #pragma unroll
    for (int ti = 0; ti < 4; ++ti) {
      #pragma unroll
      for (int j = 0; j < 4; ++j) {
        const int r = ti * 16 + kg * 4 + j;
        const float bmx = fmaxf(fmaxf(wmaxs[0 * 64 + r], wmaxs[1 * 64 + r]),
                                fmaxf(wmaxs[2 * 64 + r], wmaxs[3 * 64 + r]));
        float se = 0.f;
        #pragma unroll
        for (int tj = 0; tj < 4; ++tj) se += expf(acc[ti][tj][j] - bmx);
        #pragma unroll
        for (int msk = 8; msk >= 1; msk >>= 1) se += __shfl_xor(se, msk);
        if (l15 == 0) wsums[wid * 64 + r] = se;
      }
    }
    __syncthreads();

    if (tid < 64) {
      const int r = tid;
      const float bmx = fmaxf(fmaxf(wmaxs[0 * 64 + r], wmaxs[1 * 64 + r]),
                              fmaxf(wmaxs[2 * 64 + r], wmaxs[3 * 64 + r]));
      const float s = wsums[0 * 64 + r] + wsums[1 * 64 + r] +
                      wsums[2 * 64 + r] + wsums[3 * 64 + r];
      pmax_g[(size_t)half * NN + row0 + r] = bmx;
      psum_g[(size_t)half * NN + row0 + r] = s;
    }
  }
}

// ---------------- K4: final scalar reduce (combines proto halves exactly) -------------
__global__ void k_final(const float* __restrict__ rowsum, const float* __restrict__ pos_e,
                        const float* __restrict__ diag_e, const float* __restrict__ pmax_g,
                        const float* __restrict__ psum_g, const float* __restrict__ zl_g,
                        float* __restrict__ out) {
  __shared__ float redA[4], redB[4];
  const int tid = threadIdx.x;
  float sa = 0.f, sb = 0.f;
  for (int i = tid; i < NN; i += 256) {
    sa += logf(rowsum[i] - diag_e[i]) - logf(pos_e[i]);
    const float m0 = pmax_g[i], m1 = pmax_g[NN + i];
    const float M = fmaxf(m0, m1);
    const float s = psum_g[i] * expf(m0 - M) + psum_g[NN + i] * expf(m1 - M);
    sb += M + logf(s) - zl_g[i];
  }
  const int lane = tid & 63, wv = tid >> 6;
  #pragma unroll
  for (int k = 32; k >= 1; k >>= 1) { sa += __shfl_xor(sa, k); sb += __shfl_xor(sb, k); }
  if (lane == 0) { redA[wv] = sa; redB[wv] = sb; }
  __syncthreads();
  if (tid == 0) {
    const float la = redA[0] + redA[1] + redA[2] + redA[3];
    const float lb = redB[0] + redB[1] + redB[2] + redB[3];
    out[0] = la / (float)NN + lb / (float)NN;
  }
}

extern "C" void kernel_launch(void* const* d_in, const int* in_sizes, int n_in,
                              void* d_out, int out_size, void* d_ws, size_t ws_size,
                              hipStream_t stream) {
  (void)in_sizes; (void)n_in; (void)out_size; (void)ws_size;
  const float* si  = (const float*)d_in[0];
  const float* sj  = (const float*)d_in[1];
  const float* ci  = (const float*)d_in[2];
  const float* cj  = (const float*)d_in[3];
  const float* pi  = (const float*)d_in[4];
  const float* pj  = (const float*)d_in[5];
  const int*   lab = (const int*)d_in[6];
  const float* cst = (const float*)d_in[7];
  const float* cca = (const float*)d_in[8];
  const float* cpl = (const float*)d_in[9];
  const float* cnc = (const float*)d_in[10];

  // ws layout (~3.6 MB): small f32 arrays + bf16 feats/centroids
  float* ws     = (float*)d_ws;
  float* rowsum = ws;                          // 4096
  float* pos_e  = rowsum + NN;                 // 4096
  float* diag_e = pos_e + NN;                  // 4096
  float* pmax_g = diag_e + NN;                 // 2*4096
  float* psum_g = pmax_g + 2 * NN;             // 2*4096
  float* zl_g   = psum_g + 2 * NN;             // 4096
  __hip_bfloat16* fbf = (__hip_bfloat16*)(zl_g + NN);           // 3*4096*128 bf16 = 3 MB
  __hip_bfloat16* cbf = fbf + (size_t)3 * NN * DD;              // 3*512*128 bf16 = 384 KB

  k_normprep<<<dim3(NN / 8 + CC / 8, 3), 512, 0, stream>>>(si, sj, ci, cj, pi, pj,
                                                           cst, cca, cpl, cnc, fbf, cbf, rowsum);
  k_main<<<NSIM + NPROTO, 256, 0, stream>>>(fbf, cbf, lab, rowsum, pos_e, diag_e,
                                            pmax_g, psum_g, zl_g);
  k_final<<<1, 256, 0, stream>>>(rowsum, pos_e, diag_e, pmax_g, psum_g, zl_g, (float*)d_out);
}